// Round 11
// baseline (444.857 us; speedup 1.0000x reference)
//
#include <hip/hip_runtime.h>
#include <hip/hip_bf16.h>

// GPTNeoXAttention + CAM mask pipeline, MI355X (gfx950)
// B=4 S=1024 HID=2048 NH=16 HD=128 ROT=32, sb=rb=103
//
// R11: R10 + __launch_bounds__(256,4) on both GEMMs (was 3).
// R9/R10 established the GEMMs are latency-bound; 4 blocks/CU caps
// VGPR at 64 (+64 AGPR = 128/wave) — K-loop live set ~44 fits.

#define S_LEN 1024
#define NHEAD 16
#define HDIM  128
#define HID   2048
#define SB    103
#define RB    103
#define TMIN  206
#define NT    818

typedef __bf16 bf16x8 __attribute__((ext_vector_type(8)));
typedef __bf16 bf16x4 __attribute__((ext_vector_type(4)));
typedef float  f32x4  __attribute__((ext_vector_type(4)));

#define PLDS_STRIDE 648

// ---------------- threefry2x32 (JAX-compatible) ----------------
__device__ __forceinline__ void tf2x32(unsigned k0, unsigned k1,
                                       unsigned x0, unsigned x1,
                                       unsigned& o0, unsigned& o1) {
  unsigned ks2 = k0 ^ k1 ^ 0x1BD11BDAu;
  x0 += k0; x1 += k1;
#define TFR(r) { x0 += x1; x1 = (x1 << r) | (x1 >> (32 - r)); x1 ^= x0; }
  TFR(13) TFR(15) TFR(26) TFR(6)   x0 += k1;  x1 += ks2 + 1u;
  TFR(17) TFR(29) TFR(16) TFR(24)  x0 += ks2; x1 += k0 + 2u;
  TFR(13) TFR(15) TFR(26) TFR(6)   x0 += k0;  x1 += k1 + 3u;
  TFR(17) TFR(29) TFR(16) TFR(24)  x0 += k1;  x1 += ks2 + 4u;
  TFR(13) TFR(15) TFR(26) TFR(6)   x0 += ks2; x1 += k0 + 5u;
#undef TFR
  o0 = x0; o1 = x1;
}
__device__ __forceinline__ float tfu(unsigned b) {
  return __builtin_bit_cast(float, (b >> 9) | 0x3f800000u) - 1.0f;
}

// ---------------- fused preprocessing: cast X + transpose Wqkv + transpose Wd ----------------
__global__ __launch_bounds__(256) void k_prep(const float* __restrict__ hs,
    const float* __restrict__ Wqkv, const float* __restrict__ Wd,
    __hip_bfloat16* __restrict__ Xb, __hip_bfloat16* __restrict__ WqkvT,
    __hip_bfloat16* __restrict__ WdT) {
  __shared__ float tile[32][33];
  const int bid = blockIdx.x;
  const int tid = threadIdx.x;
  if (bid < 8192) {
    int i = bid * 256 + tid;
    float4 v = ((const float4*)hs)[i];
    __hip_bfloat162 lo = __float22bfloat162_rn(make_float2(v.x, v.y));
    __hip_bfloat162 hi = __float22bfloat162_rn(make_float2(v.z, v.w));
    ((__hip_bfloat162*)Xb)[2*i]   = lo;
    ((__hip_bfloat162*)Xb)[2*i+1] = hi;
    return;
  }
  const float* W; __hip_bfloat16* Wt; int N, n0, k0;
  if (bid < 20480) {
    int b2 = bid - 8192;
    W = Wqkv; Wt = WqkvT; N = 6144;
    n0 = (b2 % 192) * 32; k0 = (b2 / 192) * 32;
  } else {
    int b3 = bid - 20480;
    W = Wd; Wt = WdT; N = 2048;
    n0 = (b3 % 64) * 32; k0 = (b3 / 64) * 32;
  }
  const int tx = tid & 31, ty = tid >> 5;
  #pragma unroll
  for (int i = 0; i < 32; i += 8)
    tile[ty + i][tx] = W[(size_t)(k0 + ty + i) * N + n0 + tx];
  __syncthreads();
  #pragma unroll
  for (int i = 0; i < 32; i += 8)
    Wt[(size_t)(n0 + ty + i) * 2048 + k0 + tx] = __float2bfloat16(tile[tx][ty + i]);
}

// ---------------- pure bf16 transpose: Vup [bh][k][d] -> Vt [bh][d][k] ----------------
__global__ __launch_bounds__(256) void k_vtrans2(const __hip_bfloat16* __restrict__ Vup,
                                                 __hip_bfloat16* __restrict__ Vt) {
  __shared__ unsigned short tile[32][33];
  int k0 = blockIdx.x * 32, d0 = blockIdx.y * 32, bh = blockIdx.z;
  int tx = threadIdx.x, ty = threadIdx.y;
  const unsigned short* src = (const unsigned short*)Vup;
  unsigned short* dst = (unsigned short*)Vt;
  #pragma unroll
  for (int i = 0; i < 32; i += 8)
    tile[ty + i][tx] = src[((size_t)bh * S_LEN + (k0 + ty + i)) * HDIM + d0 + tx];
  __syncthreads();
  #pragma unroll
  for (int i = 0; i < 32; i += 8)
    dst[((size_t)bh * HDIM + (d0 + ty + i)) * S_LEN + k0 + tx] = tile[tx][ty + i];
}

// ---------------- 128x128 bf16 MFMA GEMM core (R2, known-best) ----------------
__device__ __forceinline__ void gemm128(const char* __restrict__ A, const char* __restrict__ Bt,
                                        int K, long rowA0, long rowB0, char* lds,
                                        f32x4 (&acc)[4][4]) {
  const int tid  = threadIdx.x;
  const int lane = tid & 63;
  const int wave = tid >> 6;
  const int wm = wave >> 1, wn = wave & 1;
  const int l4  = lane >> 2;
  const int lkb = (lane & 3) * 16;
  const int rlo = lane & 15;
  const int khi = (lane >> 4) * 16;
  const long strA = (long)K * 2;
  for (int k0 = 0; k0 < K; k0 += 32) {
    #pragma unroll
    for (int q = 0; q < 2; q++) {
      long ra = rowA0 + wave*32 + q*16 + l4;
      const char* ga = A + ra*strA + (long)k0*2 + lkb;
      __builtin_amdgcn_global_load_lds((const __attribute__((address_space(1))) void*)ga,
          (__attribute__((address_space(3))) void*)(lds + wave*2048 + q*1024), 16, 0, 0);
      long rbn = rowB0 + wave*32 + q*16 + l4;
      const char* gb = Bt + rbn*strA + (long)k0*2 + lkb;
      __builtin_amdgcn_global_load_lds((const __attribute__((address_space(1))) void*)gb,
          (__attribute__((address_space(3))) void*)(lds + 8192 + wave*2048 + q*1024), 16, 0, 0);
    }
    __syncthreads();
    bf16x8 af[4], bfr[4];
    #pragma unroll
    for (int mf = 0; mf < 4; mf++)
      af[mf] = *(const bf16x8*)(lds + (wm*64 + mf*16 + rlo)*64 + khi);
    #pragma unroll
    for (int nf = 0; nf < 4; nf++)
      bfr[nf] = *(const bf16x8*)(lds + 8192 + (wn*64 + nf*16 + rlo)*64 + khi);
    #pragma unroll
    for (int mf = 0; mf < 4; mf++)
      #pragma unroll
      for (int nf = 0; nf < 4; nf++)
        acc[mf][nf] = __builtin_amdgcn_mfma_f32_16x16x32_bf16(af[mf], bfr[nf], acc[mf][nf], 0, 0, 0);
    __syncthreads();
  }
}

// ---------------- GEMM qkv + bias + RoPE + scatter ----------------
__global__ __launch_bounds__(256, 4) void k_gemm_qkv(const __hip_bfloat16* __restrict__ Xb,
    const __hip_bfloat16* __restrict__ WqkvT, const float* __restrict__ bqkv,
    const int* __restrict__ pid,
    __hip_bfloat16* __restrict__ Qb, __hip_bfloat16* __restrict__ Kb, float* __restrict__ Vf) {
  __shared__ __align__(16) char lds[16384];
  f32x4 acc[4][4];
  #pragma unroll
  for (int m = 0; m < 4; m++)
    #pragma unroll
    for (int n = 0; n < 4; n++)
      #pragma unroll
      for (int r = 0; r < 4; r++) acc[m][n][r] = 0.f;
  // XCD-bijective swizzle: nwg = 1536 = 8 * 192
  int flat = blockIdx.y * 32 + blockIdx.x;
  int swz = (flat & 7) * 192 + (flat >> 3);
  int bm = swz & 31, bn = swz >> 5;
  gemm128((const char*)Xb, (const char*)WqkvT, HID, (long)bm*128, (long)bn*128, lds, acc);
  const int lane = threadIdx.x & 63, wave = threadIdx.x >> 6;
  const int wm = wave >> 1, wn = wave & 1;
  const int colbase = bn*128 + wn*64;
  const int rowbase = bm*128 + wm*64 + (lane >> 4) * 4;
  // bias
  #pragma unroll
  for (int nf = 0; nf < 4; nf++) {
    int col = colbase + nf*16 + (lane & 15);
    float bias = bqkv[col];
    #pragma unroll
    for (int mf = 0; mf < 4; mf++)
      #pragma unroll
      for (int r = 0; r < 4; r++) acc[mf][nf][r] += bias;
  }
  // RoPE: pair (i, i+16) in frags nf=0,1 at same lane iff colbase%384 in {0,128}
  const int jb = colbase % 384;
  if (jb == 0 || jb == 128) {
    const int i = lane & 15;
    const float invf = exp2f(-(float)i * 0.8304820237218406f); // 10000^(-i/16)
    #pragma unroll
    for (int mf = 0; mf < 4; mf++) {
      #pragma unroll
      for (int r = 0; r < 4; r++) {
        int row = rowbase + mf*16 + r;
        int b = row >> 10, s = row & 1023;
        float th = (float)pid[b * S_LEN + s] * invf;
        float sn, cs;
        sincosf(th, &sn, &cs);
        float x1 = acc[mf][0][r], x2 = acc[mf][1][r];
        acc[mf][0][r] = x1*cs - x2*sn;
        acc[mf][1][r] = x2*cs + x1*sn;
      }
    }
  }
  // scatter
  #pragma unroll
  for (int mf = 0; mf < 4; mf++) {
    #pragma unroll
    for (int nf = 0; nf < 4; nf++) {
      int col = colbase + nf*16 + (lane & 15);
      int h = col / 384, j = col % 384;
      #pragma unroll
      for (int r = 0; r < 4; r++) {
        int row = rowbase + mf*16 + r;
        int b = row >> 10, s = row & 1023;
        size_t base = ((size_t)(b*NHEAD + h)*S_LEN + s)*HDIM;
        float v = acc[mf][nf][r];
        if (j < 128)      Qb[base + j]       = __float2bfloat16(v);
        else if (j < 256) Kb[base + j - 128] = __float2bfloat16(v);
        else              Vf[base + j - 256] = v;
      }
    }
  }
}

// ---------------- GEMM out-proj + bias ----------------
__global__ __launch_bounds__(256, 4) void k_gemm_out(const __hip_bfloat16* __restrict__ Ab,
    const __hip_bfloat16* __restrict__ WdT, const float* __restrict__ bd,
    float* __restrict__ Out) {
  __shared__ __align__(16) char lds[16384];
  f32x4 acc[4][4];
  #pragma unroll
  for (int m = 0; m < 4; m++)
    #pragma unroll
    for (int n = 0; n < 4; n++)
      #pragma unroll
      for (int r = 0; r < 4; r++) acc[m][n][r] = 0.f;
  // XCD-bijective swizzle: nwg = 512 = 8 * 64
  int flat = blockIdx.y * 32 + blockIdx.x;
  int swz = (flat & 7) * 64 + (flat >> 3);
  int bm = swz & 31, bn = swz >> 5;
  gemm128((const char*)Ab, (const char*)WdT, HID, (long)bm*128, (long)bn*128, lds, acc);
  const int lane = threadIdx.x & 63, wave = threadIdx.x >> 6;
  const int wm = wave >> 1, wn = wave & 1;
  const int colbase = bn*128 + wn*64;
  const int rowbase = bm*128 + wm*64 + (lane >> 4) * 4;
  #pragma unroll
  for (int nf = 0; nf < 4; nf++) {
    int col = colbase + nf*16 + (lane & 15);
    float bias = bd[col];
    #pragma unroll
    for (int mf = 0; mf < 4; mf++)
      #pragma unroll
      for (int r = 0; r < 4; r++) {
        int row = rowbase + mf*16 + r;
        Out[(size_t)row * HID + col] = acc[mf][nf][r] + bias;
      }
  }
}

// ---------------- banded flash attention (R5 structure + occupancy cap) ----------------
__device__ __forceinline__ bf16x8 lds_load8(const char* p) {
  bf16x4 lo = *(const bf16x4*)p;
  bf16x4 hi = *(const bf16x4*)(p + 8);
  bf16x8 v;
  v[0]=lo[0]; v[1]=lo[1]; v[2]=lo[2]; v[3]=lo[3];
  v[4]=hi[0]; v[5]=hi[1]; v[6]=hi[2]; v[7]=hi[3];
  return v;
}

template<int PHASE>
__global__ __launch_bounds__(256, 3) void k_flash(const __hip_bfloat16* __restrict__ Qb,
    const __hip_bfloat16* __restrict__ Kb, const __hip_bfloat16* __restrict__ Vt,
    const float* __restrict__ amask,
    float* __restrict__ Pstart, float* __restrict__ PbT,
    __hip_bfloat16* __restrict__ Aout) {
  const int q0 = blockIdx.x * 64;
  const int bh = blockIdx.y;                 // PHASE0: h, PHASE1: b*16+h
  const int b  = PHASE ? (bh >> 4) : 0;
  const int h  = PHASE ? (bh & 15) : bh;
  const int tid = threadIdx.x;
  const int w = tid >> 6;
  const int lane = tid & 63;
  const int l15 = lane & 15, g = lane >> 4;

  const int t1 = (q0 >= 128) ? max(128, (q0 - 103) & ~31) : 128;
  const int nt1 = (q0 + 64 > t1) ? (q0 + 64 - t1) / 32 : 0;
  const int ntiles = 4 + nt1;
  const int nfrags = ntiles * 2;             // <= 20

  __shared__ float redm[4][64];
  __shared__ float reds[4][64];
  __shared__ __align__(16) char plds[(PHASE ? 64 * PLDS_STRIDE : 16)];

  const size_t qkbase = (size_t)bh * S_LEN;

  bf16x8 af[4][4];
  #pragma unroll
  for (int mi = 0; mi < 4; mi++)
    #pragma unroll
    for (int dt = 0; dt < 4; dt++)
      af[mi][dt] = *(const bf16x8*)(Qb + (qkbase + q0 + mi*16 + l15)*HDIM + dt*32 + g*8);

  int kb[5];
  #pragma unroll
  for (int fi = 0; fi < 5; fi++) {
    int f = w + fi*4;
    if (f < nfrags) {
      int ti = f >> 1;
      int kt = (ti < 4) ? ti*32 : t1 + (ti-4)*32;
      kb[fi] = kt + (f & 1)*16;
    } else kb[fi] = -1;
  }

  f32x4 sacc[4][5];
  #pragma unroll
  for (int mi = 0; mi < 4; mi++)
    #pragma unroll
    for (int fi = 0; fi < 5; fi++)
      #pragma unroll
      for (int r = 0; r < 4; r++) sacc[mi][fi][r] = 0.f;

  #pragma unroll
  for (int fi = 0; fi < 5; fi++) {
    if (kb[fi] < 0) continue;
    #pragma unroll
    for (int dt = 0; dt < 4; dt++) {
      bf16x8 bfr = *(const bf16x8*)(Kb + (qkbase + kb[fi] + l15)*HDIM + dt*32 + g*8);
      #pragma unroll
      for (int mi = 0; mi < 4; mi++)
        sacc[mi][fi] = __builtin_amdgcn_mfma_f32_16x16x32_bf16(af[mi][dt], bfr, sacc[mi][fi], 0, 0, 0);
    }
  }

  #pragma unroll
  for (int fi = 0; fi < 5; fi++) {
    if (kb[fi] < 0) continue;
    int kcol = kb[fi] + l15;
    float amv = amask[b * S_LEN + kcol];
    #pragma unroll
    for (int mi = 0; mi < 4; mi++)
      #pragma unroll
      for (int r = 0; r < 4; r++) {
        int q = q0 + mi*16 + g*4 + r;
        bool ok = (kcol <= q) && ((kcol < SB) || (kcol + RB >= q));
        sacc[mi][fi][r] = ok ? sacc[mi][fi][r] * 0.08838834764831845f + amv : -3.0e38f;
      }
  }

  float rmax[4][4];
  #pragma unroll
  for (int mi = 0; mi < 4; mi++)
    #pragma unroll
    for (int r = 0; r < 4; r++) {
      float m = -3.4e38f;
      #pragma unroll
      for (int fi = 0; fi < 5; fi++)
        if (kb[fi] >= 0) m = fmaxf(m, sacc[mi][fi][r]);
      #pragma unroll
      for (int d = 1; d < 16; d <<= 1) m = fmaxf(m, __shfl_xor(m, d));
      rmax[mi][r] = m;
    }
  if (l15 == 0)
    #pragma unroll
    for (int mi = 0; mi < 4; mi++)
      #pragma unroll
      for (int r = 0; r < 4; r++) redm[w][mi*16 + g*4 + r] = rmax[mi][r];
  __syncthreads();
  #pragma unroll
  for (int mi = 0; mi < 4; mi++)
    #pragma unroll
    for (int r = 0; r < 4; r++) {
      int q = mi*16 + g*4 + r;
      rmax[mi][r] = fmaxf(fmaxf(redm[0][q], redm[1][q]), fmaxf(redm[2][q], redm[3][q]));
    }

  float rsum[4][4];
  #pragma unroll
  for (int mi = 0; mi < 4; mi++)
    #pragma unroll
    for (int r = 0; r < 4; r++) rsum[mi][r] = 0.f;
  #pragma unroll
  for (int fi = 0; fi < 5; fi++) {
    if (kb[fi] < 0) continue;
    #pragma unroll
    for (int mi = 0; mi < 4; mi++)
      #pragma unroll
      for (int r = 0; r < 4; r++) {
        float e = __expf(sacc[mi][fi][r] - rmax[mi][r]);
        sacc[mi][fi][r] = e;
        rsum[mi][r] += e;
      }
  }
  #pragma unroll
  for (int mi = 0; mi < 4; mi++)
    #pragma unroll
    for (int r = 0; r < 4; r++) {
      float s = rsum[mi][r];
      #pragma unroll
      for (int d = 1; d < 16; d <<= 1) s += __shfl_xor(s, d);
      rsum[mi][r] = s;
    }
  if (l15 == 0)
    #pragma unroll
    for (int mi = 0; mi < 4; mi++)
      #pragma unroll
      for (int r = 0; r < 4; r++) reds[w][mi*16 + g*4 + r] = rsum[mi][r];
  __syncthreads();
  float inv[4][4];
  #pragma unroll
  for (int mi = 0; mi < 4; mi++)
    #pragma unroll
    for (int r = 0; r < 4; r++) {
      int q = mi*16 + g*4 + r;
      inv[mi][r] = 1.0f / (reds[0][q] + reds[1][q] + reds[2][q] + reds[3][q]);
    }

  if constexpr (PHASE == 0) {
    #pragma unroll
    for (int fi = 0; fi < 5; fi++) {
      if (kb[fi] < 0) continue;
      int kcol = kb[fi] + l15;
      #pragma unroll
      for (int mi = 0; mi < 4; mi++)
        #pragma unroll
        for (int r = 0; r < 4; r++) {
          int q = q0 + mi*16 + g*4 + r;
          float p = sacc[mi][fi][r] * inv[mi][r];
          if (kcol < 128)
            Pstart[((size_t)h*128 + kcol)*S_LEN + q] = p;
          if (kcol >= SB && kcol < 1023 && kcol <= q && q - kcol <= RB)
            PbT[((size_t)h*920 + (kcol - SB))*104 + (q - kcol)] = p;
        }
    }
  } else {
    #pragma unroll
    for (int fi = 0; fi < 5; fi++) {
      if (kb[fi] < 0) continue;
      int cc = (w + fi*4)*16 + l15;
      #pragma unroll
      for (int mi = 0; mi < 4; mi++)
        #pragma unroll
        for (int r = 0; r < 4; r++) {
          int qs = mi*16 + g*4 + r;
          *(__hip_bfloat16*)(plds + qs*PLDS_STRIDE + cc*2) =
              __float2bfloat16(sacc[mi][fi][r] * inv[mi][r]);
        }
    }
    __syncthreads();
    f32x4 pacc[4][2];
    #pragma unroll
    for (int mi = 0; mi < 4; mi++)
      #pragma unroll
      for (int nj = 0; nj < 2; nj++)
        #pragma unroll
        for (int r = 0; r < 4; r++) pacc[mi][nj][r] = 0.f;
    for (int ti = 0; ti < ntiles; ti++) {
      int kt = (ti < 4) ? ti*32 : t1 + (ti-4)*32;
      int cb = ti*32;
      bf16x8 pa[4];
      #pragma unroll
      for (int mi = 0; mi < 4; mi++)
        pa[mi] = lds_load8(plds + (mi*16 + l15)*PLDS_STRIDE + (cb + g*8)*2);
      #pragma unroll
      for (int nj = 0; nj < 2; nj++) {
        int d = w*32 + nj*16 + l15;
        bf16x8 vb = *(const bf16x8*)(Vt + ((size_t)bh*HDIM + d)*S_LEN + kt + g*8);
        #pragma unroll
        for (int mi = 0; mi < 4; mi++)
          pacc[mi][nj] = __builtin_amdgcn_mfma_f32_16x16x32_bf16(pa[mi], vb, pacc[mi][nj], 0, 0, 0);
      }
    }
    #pragma unroll
    for (int mi = 0; mi < 4; mi++)
      #pragma unroll
      for (int nj = 0; nj < 2; nj++)
        #pragma unroll
        for (int r = 0; r < 4; r++) {
          int q = q0 + mi*16 + g*4 + r;
          int d = w*32 + nj*16 + l15;
          Aout[((size_t)b*S_LEN + q)*HID + h*HDIM + d] = __float2bfloat16(pacc[mi][nj][r]);
        }
  }
}

// ---------------- stats: sstart + band merged (wave-per-column prefix scans) ----------------
__global__ __launch_bounds__(256) void k_scans(const float* __restrict__ Pstart,
                                               const float* __restrict__ PbT,
                                               float* __restrict__ Sstart,
                                               float* __restrict__ Band) {
  int lane = threadIdx.x & 63;
  if (blockIdx.x < 412) {
    int wid = blockIdx.x*4 + (threadIdx.x >> 6);
    if (wid >= NHEAD * SB) return;
    int h = wid / SB, k = wid % SB;
    const float* col = Pstart + ((size_t)h*128 + k)*S_LEN;
    float carry = 0.f;
    for (int seg = 0; seg < 16; seg++) {
      int q = seg*64 + lane;
      float v = col[q];
      #pragma unroll
      for (int d = 1; d < 64; d <<= 1) {
        float u = __shfl_up(v, d);
        if (lane >= d) v += u;
      }
      float tot = carry + v;
      int t = q + 1;
      if (t >= TMIN && t < S_LEN)
        Sstart[((size_t)h*SB + k)*NT + (t - TMIN)] = tot;
      carry += __shfl(v, 63);
    }
  } else {
    int wid = (blockIdx.x - 412)*4 + (threadIdx.x >> 6);
    if (wid >= NHEAD * 920) return;
    int h = wid / 920, kk = wid % 920;
    int k = kk + SB;
    const float* col = PbT + ((size_t)h*920 + kk)*104;
    float carry = 0.f;
    #pragma unroll
    for (int seg = 0; seg < 2; seg++) {
      int i = seg*64 + lane;
      bool valid = (i <= 102) && (k + i <= 1022);
      float v = valid ? col[i] : 0.f;
      #pragma unroll
      for (int d = 1; d < 64; d <<= 1) {
        float u = __shfl_up(v, d);
        if (lane >= d) v += u;
      }
      float tot = carry + v;
      int t = k + i + 1;
      if (valid && t >= TMIN && t < S_LEN) {
        int j = 102 - i;
        Band[((size_t)h*S_LEN + t)*SB + j] = tot;
      }
      carry += __shfl(v, 63);
    }
  }
}

// ---------------- prob + threefry bernoulli ----------------
__global__ __launch_bounds__(64) void k_mask(const float* __restrict__ Sstart,
    const float* __restrict__ Band, float* __restrict__ Mask) {
  const int t = TMIN + blockIdx.x;
  const int lane = threadIdx.x;
  const int h = lane >> 2, j = lane & 3;
  const float* bb = Band + ((size_t)h*S_LEN + t)*SB;
  float mx = -3.4e38f;
  for (int i = j; i < SB; i += 4)
    mx = fmaxf(mx, Sstart[((size_t)h*SB + i)*NT + (t - TMIN)]);
  for (int i = j; i < RB; i += 4) mx = fmaxf(mx, bb[i]);
  mx = fmaxf(mx, __shfl_xor(mx, 1));
  mx = fmaxf(mx, __shfl_xor(mx, 2));
  if (j == 0) {
    float prob = bb[0] / mx;
    prob = fminf(fmaxf(prob, 0.f), 1.f);
    unsigned a0, a1, b0, b1;
    tf2x32(0u, 42u, 0u, (unsigned)t, a0, a1);
    tf2x32(a0, a1, 0u, (unsigned)h, b0, b1);
    float u = tfu(b0 ^ b1);
    Mask[t*NHEAD + h] = (u < prob) ? 1.f : 0.f;
  }
}

// ---------------- fused CAM scan + vupdate -> Vup bf16 [bh][p][d] ----------------
__global__ __launch_bounds__(64) void k_scan(const float* __restrict__ Vf,
    const float* __restrict__ Mask, __hip_bfloat16* __restrict__ Vup) {
  const int blk = blockIdx.x;       // 0..127
  const int bh = blk >> 1, dc = blk & 1;
  const int h = bh & 15;
  const int lane = threadIdx.x;
  const int col = dc*64 + lane;
  __shared__ float ring[RB * 64];   // w ring
  __shared__ float pring[RB * 64];  // P ring
  __shared__ float marr[NT];
  for (int i = lane; i < NT; i += 64) marr[i] = Mask[(TMIN + i)*NHEAD + h];
  __syncthreads();
  const size_t vbase = (size_t)bh * S_LEN * HDIM + col;
  const size_t obase = (size_t)bh * S_LEN * HDIM + col;
  #pragma unroll 4
  for (int p = 0; p <= 103; p++)
    Vup[obase + (size_t)p * HDIM] = __float2bfloat16(Vf[vbase + (size_t)p * HDIM]);

  float S = 0.f, P = 0.f;
  float cur[8], nxt[8];
  #pragma unroll
  for (int u = 0; u < 8; u++)
    cur[u] = Vf[vbase + (size_t)(TMIN - RB + u) * HDIM];
  for (int t0 = TMIN; t0 < S_LEN; t0 += 8) {
    #pragma unroll
    for (int u = 0; u < 8; u++) {
      int t = t0 + 8 + u;
      if (t < S_LEN + 8) nxt[u] = Vf[vbase + (size_t)min(t - RB, S_LEN - 1) * HDIM];
    }
    float olds[8], plo[8];
    #pragma unroll
    for (int u = 0; u < 8; u++) {
      int t = t0 + u;
      olds[u] = (t >= TMIN + RB) ? ring[(t % RB)*64 + lane] : 0.f;
      plo[u]  = (t >= TMIN + RB) ? pring[(t % RB)*64 + lane] : 0.f;  // = P(t-103)
    }
    #pragma unroll
    for (int u = 0; u < 8; u++) {
      int t = t0 + u;
      float a = fmaf(S, (1.f/103.f), cur[u]);
      float w = marr[t - TMIN] * a;
      P += w;
      float vnext = (u < 7) ? cur[u + 1] : nxt[0];
      float Plo = (t <= 308) ? 0.f : plo[u];
      Vup[obase + (size_t)(t - 102) * HDIM] = __float2bfloat16(vnext + (P - Plo) * (1.f/103.f));
      pring[(t % RB)*64 + lane] = P;
      ring[(t % RB)*64 + lane] = w;
      S += w - olds[u];
      cur[u] = nxt[u];
    }
  }
  const float Pfin = P;
  for (int p = 922; p <= 1023; p++) {
    float Plo = pring[((p - 1) % RB)*64 + lane];
    float v = Vf[vbase + (size_t)p * HDIM];
    Vup[obase + (size_t)p * HDIM] = __float2bfloat16(v + (Pfin - Plo) * (1.f/103.f));
  }
}

extern "C" void kernel_launch(void* const* d_in, const int* in_sizes, int n_in,
                              void* d_out, int out_size, void* d_ws, size_t ws_size,
                              hipStream_t stream) {
  const float* hs    = (const float*)d_in[0];
  const float* amask = (const float*)d_in[1];
  const int*   pid   = (const int*)d_in[2];
  const float* Wqkv  = (const float*)d_in[3];
  const float* bqkv  = (const float*)d_in[4];
  const float* Wd    = (const float*)d_in[5];
  const float* bd    = (const float*)d_in[6];
  float* Out = (float*)d_out;

  char* ws = (char*)d_ws;
  size_t off = 0;
  auto alloc = [&](size_t bytes) {
    char* p = ws + off;
    off += (bytes + 255) & ~(size_t)255;
    return p;
  };
  __hip_bfloat16* Xb     = (__hip_bfloat16*)alloc(16777216);  // 4096x2048 bf16
  __hip_bfloat16* WqkvT  = (__hip_bfloat16*)alloc(25165824);  // 6144x2048 bf16
  __hip_bfloat16* WdT    = (__hip_bfloat16*)alloc(8388608);   // 2048x2048 bf16
  __hip_bfloat16* Qb     = (__hip_bfloat16*)alloc(16777216);  // (4,16,1024,128) bf16
  __hip_bfloat16* Kb     = (__hip_bfloat16*)alloc(16777216);
  float*          Vf     = (float*)alloc(33554432);           // (4,16,1024,128) f32
  __hip_bfloat16* Vup    = (__hip_bfloat16*)alloc(16777216);  // (64,1024,128) bf16
  __hip_bfloat16* Vt     = (__hip_bfloat16*)alloc(16777216);  // (64,128,1024) bf16
  float*          Pstart = (float*)alloc(8388608);            // (16,128,1024) f32
  float*          PbT    = (float*)alloc(6123520);            // (16,920,104) f32
  float*          Sstart = (float*)alloc(5392256);            // (16,103,818) f32
  float*          Band   = (float*)alloc(6750208);            // (16,1024,103) f32
  float*          Mask   = (float*)alloc(65536);              // (1024,16) f32
  __hip_bfloat16* Aout   = (__hip_bfloat16*)alloc(16777216);  // 4096x2048 bf16

  k_prep<<<24576, 256, 0, stream>>>(hs, Wqkv, Wd, Xb, WqkvT, WdT);
  k_gemm_qkv<<<dim3(32, 48), 256, 0, stream>>>(Xb, WqkvT, bqkv, pid, Qb, Kb, Vf);
  k_flash<0><<<dim3(16, 16), 256, 0, stream>>>(Qb, Kb, nullptr, amask, Pstart, PbT, nullptr);
  k_scans<<<4092, 256, 0, stream>>>(Pstart, PbT, Sstart, Band);
  k_mask<<<818, 64, 0, stream>>>(Sstart, Band, Mask);
  k_scan<<<128, 64, 0, stream>>>(Vf, Mask, Vup);
  k_vtrans2<<<dim3(32, 4, 64), dim3(32, 8), 0, stream>>>(Vup, Vt);
  k_flash<1><<<dim3(16, 64), 256, 0, stream>>>(Qb, Kb, Vt, amask, nullptr, nullptr, Aout);
  k_gemm_out<<<dim3(32, 16), 256, 0, stream>>>(Aout, WdT, bd, Out);
}

// Round 12
// 422.039 us; speedup vs baseline: 1.0541x; 1.0541x over previous
//
#include <hip/hip_runtime.h>
#include <hip/hip_bf16.h>

// GPTNeoXAttention + CAM mask pipeline, MI355X (gfx950)
// B=4 S=1024 HID=2048 NH=16 HD=128 ROT=32, sb=rb=103
//
// R12: revert to R10 (GEMMs + flash at __launch_bounds__(256,3)).
// R11's (256,4) on GEMMs spilled (WRITE_SIZE 66->98 MB, qkv 140->158 us).
// Occupancy ladder bracketed: 2 blk/CU=175us, 3=140us (best), 4=158us (spills).

#define S_LEN 1024
#define NHEAD 16
#define HDIM  128
#define HID   2048
#define SB    103
#define RB    103
#define TMIN  206
#define NT    818

typedef __bf16 bf16x8 __attribute__((ext_vector_type(8)));
typedef __bf16 bf16x4 __attribute__((ext_vector_type(4)));
typedef float  f32x4  __attribute__((ext_vector_type(4)));

#define PLDS_STRIDE 648

// ---------------- threefry2x32 (JAX-compatible) ----------------
__device__ __forceinline__ void tf2x32(unsigned k0, unsigned k1,
                                       unsigned x0, unsigned x1,
                                       unsigned& o0, unsigned& o1) {
  unsigned ks2 = k0 ^ k1 ^ 0x1BD11BDAu;
  x0 += k0; x1 += k1;
#define TFR(r) { x0 += x1; x1 = (x1 << r) | (x1 >> (32 - r)); x1 ^= x0; }
  TFR(13) TFR(15) TFR(26) TFR(6)   x0 += k1;  x1 += ks2 + 1u;
  TFR(17) TFR(29) TFR(16) TFR(24)  x0 += ks2; x1 += k0 + 2u;
  TFR(13) TFR(15) TFR(26) TFR(6)   x0 += k0;  x1 += k1 + 3u;
  TFR(17) TFR(29) TFR(16) TFR(24)  x0 += k1;  x1 += ks2 + 4u;
  TFR(13) TFR(15) TFR(26) TFR(6)   x0 += ks2; x1 += k0 + 5u;
#undef TFR
  o0 = x0; o1 = x1;
}
__device__ __forceinline__ float tfu(unsigned b) {
  return __builtin_bit_cast(float, (b >> 9) | 0x3f800000u) - 1.0f;
}

// ---------------- fused preprocessing: cast X + transpose Wqkv + transpose Wd ----------------
__global__ __launch_bounds__(256) void k_prep(const float* __restrict__ hs,
    const float* __restrict__ Wqkv, const float* __restrict__ Wd,
    __hip_bfloat16* __restrict__ Xb, __hip_bfloat16* __restrict__ WqkvT,
    __hip_bfloat16* __restrict__ WdT) {
  __shared__ float tile[32][33];
  const int bid = blockIdx.x;
  const int tid = threadIdx.x;
  if (bid < 8192) {
    int i = bid * 256 + tid;
    float4 v = ((const float4*)hs)[i];
    __hip_bfloat162 lo = __float22bfloat162_rn(make_float2(v.x, v.y));
    __hip_bfloat162 hi = __float22bfloat162_rn(make_float2(v.z, v.w));
    ((__hip_bfloat162*)Xb)[2*i]   = lo;
    ((__hip_bfloat162*)Xb)[2*i+1] = hi;
    return;
  }
  const float* W; __hip_bfloat16* Wt; int N, n0, k0;
  if (bid < 20480) {
    int b2 = bid - 8192;
    W = Wqkv; Wt = WqkvT; N = 6144;
    n0 = (b2 % 192) * 32; k0 = (b2 / 192) * 32;
  } else {
    int b3 = bid - 20480;
    W = Wd; Wt = WdT; N = 2048;
    n0 = (b3 % 64) * 32; k0 = (b3 / 64) * 32;
  }
  const int tx = tid & 31, ty = tid >> 5;
  #pragma unroll
  for (int i = 0; i < 32; i += 8)
    tile[ty + i][tx] = W[(size_t)(k0 + ty + i) * N + n0 + tx];
  __syncthreads();
  #pragma unroll
  for (int i = 0; i < 32; i += 8)
    Wt[(size_t)(n0 + ty + i) * 2048 + k0 + tx] = __float2bfloat16(tile[tx][ty + i]);
}

// ---------------- pure bf16 transpose: Vup [bh][k][d] -> Vt [bh][d][k] ----------------
__global__ __launch_bounds__(256) void k_vtrans2(const __hip_bfloat16* __restrict__ Vup,
                                                 __hip_bfloat16* __restrict__ Vt) {
  __shared__ unsigned short tile[32][33];
  int k0 = blockIdx.x * 32, d0 = blockIdx.y * 32, bh = blockIdx.z;
  int tx = threadIdx.x, ty = threadIdx.y;
  const unsigned short* src = (const unsigned short*)Vup;
  unsigned short* dst = (unsigned short*)Vt;
  #pragma unroll
  for (int i = 0; i < 32; i += 8)
    tile[ty + i][tx] = src[((size_t)bh * S_LEN + (k0 + ty + i)) * HDIM + d0 + tx];
  __syncthreads();
  #pragma unroll
  for (int i = 0; i < 32; i += 8)
    dst[((size_t)bh * HDIM + (d0 + ty + i)) * S_LEN + k0 + tx] = tile[tx][ty + i];
}

// ---------------- 128x128 bf16 MFMA GEMM core (R2, known-best) ----------------
__device__ __forceinline__ void gemm128(const char* __restrict__ A, const char* __restrict__ Bt,
                                        int K, long rowA0, long rowB0, char* lds,
                                        f32x4 (&acc)[4][4]) {
  const int tid  = threadIdx.x;
  const int lane = tid & 63;
  const int wave = tid >> 6;
  const int wm = wave >> 1, wn = wave & 1;
  const int l4  = lane >> 2;
  const int lkb = (lane & 3) * 16;
  const int rlo = lane & 15;
  const int khi = (lane >> 4) * 16;
  const long strA = (long)K * 2;
  for (int k0 = 0; k0 < K; k0 += 32) {
    #pragma unroll
    for (int q = 0; q < 2; q++) {
      long ra = rowA0 + wave*32 + q*16 + l4;
      const char* ga = A + ra*strA + (long)k0*2 + lkb;
      __builtin_amdgcn_global_load_lds((const __attribute__((address_space(1))) void*)ga,
          (__attribute__((address_space(3))) void*)(lds + wave*2048 + q*1024), 16, 0, 0);
      long rbn = rowB0 + wave*32 + q*16 + l4;
      const char* gb = Bt + rbn*strA + (long)k0*2 + lkb;
      __builtin_amdgcn_global_load_lds((const __attribute__((address_space(1))) void*)gb,
          (__attribute__((address_space(3))) void*)(lds + 8192 + wave*2048 + q*1024), 16, 0, 0);
    }
    __syncthreads();
    bf16x8 af[4], bfr[4];
    #pragma unroll
    for (int mf = 0; mf < 4; mf++)
      af[mf] = *(const bf16x8*)(lds + (wm*64 + mf*16 + rlo)*64 + khi);
    #pragma unroll
    for (int nf = 0; nf < 4; nf++)
      bfr[nf] = *(const bf16x8*)(lds + 8192 + (wn*64 + nf*16 + rlo)*64 + khi);
    #pragma unroll
    for (int mf = 0; mf < 4; mf++)
      #pragma unroll
      for (int nf = 0; nf < 4; nf++)
        acc[mf][nf] = __builtin_amdgcn_mfma_f32_16x16x32_bf16(af[mf], bfr[nf], acc[mf][nf], 0, 0, 0);
    __syncthreads();
  }
}

// ---------------- GEMM qkv + bias + RoPE + scatter ----------------
__global__ __launch_bounds__(256, 3) void k_gemm_qkv(const __hip_bfloat16* __restrict__ Xb,
    const __hip_bfloat16* __restrict__ WqkvT, const float* __restrict__ bqkv,
    const int* __restrict__ pid,
    __hip_bfloat16* __restrict__ Qb, __hip_bfloat16* __restrict__ Kb, float* __restrict__ Vf) {
  __shared__ __align__(16) char lds[16384];
  f32x4 acc[4][4];
  #pragma unroll
  for (int m = 0; m < 4; m++)
    #pragma unroll
    for (int n = 0; n < 4; n++)
      #pragma unroll
      for (int r = 0; r < 4; r++) acc[m][n][r] = 0.f;
  // XCD-bijective swizzle: nwg = 1536 = 8 * 192
  int flat = blockIdx.y * 32 + blockIdx.x;
  int swz = (flat & 7) * 192 + (flat >> 3);
  int bm = swz & 31, bn = swz >> 5;
  gemm128((const char*)Xb, (const char*)WqkvT, HID, (long)bm*128, (long)bn*128, lds, acc);
  const int lane = threadIdx.x & 63, wave = threadIdx.x >> 6;
  const int wm = wave >> 1, wn = wave & 1;
  const int colbase = bn*128 + wn*64;
  const int rowbase = bm*128 + wm*64 + (lane >> 4) * 4;
  // bias
  #pragma unroll
  for (int nf = 0; nf < 4; nf++) {
    int col = colbase + nf*16 + (lane & 15);
    float bias = bqkv[col];
    #pragma unroll
    for (int mf = 0; mf < 4; mf++)
      #pragma unroll
      for (int r = 0; r < 4; r++) acc[mf][nf][r] += bias;
  }
  // RoPE: pair (i, i+16) in frags nf=0,1 at same lane iff colbase%384 in {0,128}
  const int jb = colbase % 384;
  if (jb == 0 || jb == 128) {
    const int i = lane & 15;
    const float invf = exp2f(-(float)i * 0.8304820237218406f); // 10000^(-i/16)
    #pragma unroll
    for (int mf = 0; mf < 4; mf++) {
      #pragma unroll
      for (int r = 0; r < 4; r++) {
        int row = rowbase + mf*16 + r;
        int b = row >> 10, s = row & 1023;
        float th = (float)pid[b * S_LEN + s] * invf;
        float sn, cs;
        sincosf(th, &sn, &cs);
        float x1 = acc[mf][0][r], x2 = acc[mf][1][r];
        acc[mf][0][r] = x1*cs - x2*sn;
        acc[mf][1][r] = x2*cs + x1*sn;
      }
    }
  }
  // scatter
  #pragma unroll
  for (int mf = 0; mf < 4; mf++) {
    #pragma unroll
    for (int nf = 0; nf < 4; nf++) {
      int col = colbase + nf*16 + (lane & 15);
      int h = col / 384, j = col % 384;
      #pragma unroll
      for (int r = 0; r < 4; r++) {
        int row = rowbase + mf*16 + r;
        int b = row >> 10, s = row & 1023;
        size_t base = ((size_t)(b*NHEAD + h)*S_LEN + s)*HDIM;
        float v = acc[mf][nf][r];
        if (j < 128)      Qb[base + j]       = __float2bfloat16(v);
        else if (j < 256) Kb[base + j - 128] = __float2bfloat16(v);
        else              Vf[base + j - 256] = v;
      }
    }
  }
}

// ---------------- GEMM out-proj + bias ----------------
__global__ __launch_bounds__(256, 3) void k_gemm_out(const __hip_bfloat16* __restrict__ Ab,
    const __hip_bfloat16* __restrict__ WdT, const float* __restrict__ bd,
    float* __restrict__ Out) {
  __shared__ __align__(16) char lds[16384];
  f32x4 acc[4][4];
  #pragma unroll
  for (int m = 0; m < 4; m++)
    #pragma unroll
    for (int n = 0; n < 4; n++)
      #pragma unroll
      for (int r = 0; r < 4; r++) acc[m][n][r] = 0.f;
  // XCD-bijective swizzle: nwg = 512 = 8 * 64
  int flat = blockIdx.y * 32 + blockIdx.x;
  int swz = (flat & 7) * 64 + (flat >> 3);
  int bm = swz & 31, bn = swz >> 5;
  gemm128((const char*)Ab, (const char*)WdT, HID, (long)bm*128, (long)bn*128, lds, acc);
  const int lane = threadIdx.x & 63, wave = threadIdx.x >> 6;
  const int wm = wave >> 1, wn = wave & 1;
  const int colbase = bn*128 + wn*64;
  const int rowbase = bm*128 + wm*64 + (lane >> 4) * 4;
  #pragma unroll
  for (int nf = 0; nf < 4; nf++) {
    int col = colbase + nf*16 + (lane & 15);
    float bias = bd[col];
    #pragma unroll
    for (int mf = 0; mf < 4; mf++)
      #pragma unroll
      for (int r = 0; r < 4; r++) {
        int row = rowbase + mf*16 + r;
        Out[(size_t)row * HID + col] = acc[mf][nf][r] + bias;
      }
  }
}

// ---------------- banded flash attention (R5 structure + occupancy cap) ----------------
__device__ __forceinline__ bf16x8 lds_load8(const char* p) {
  bf16x4 lo = *(const bf16x4*)p;
  bf16x4 hi = *(const bf16x4*)(p + 8);
  bf16x8 v;
  v[0]=lo[0]; v[1]=lo[1]; v[2]=lo[2]; v[3]=lo[3];
  v[4]=hi[0]; v[5]=hi[1]; v[6]=hi[2]; v[7]=hi[3];
  return v;
}

template<int PHASE>
__global__ __launch_bounds__(256, 3) void k_flash(const __hip_bfloat16* __restrict__ Qb,
    const __hip_bfloat16* __restrict__ Kb, const __hip_bfloat16* __restrict__ Vt,
    const float* __restrict__ amask,
    float* __restrict__ Pstart, float* __restrict__ PbT,
    __hip_bfloat16* __restrict__ Aout) {
  const int q0 = blockIdx.x * 64;
  const int bh = blockIdx.y;                 // PHASE0: h, PHASE1: b*16+h
  const int b  = PHASE ? (bh >> 4) : 0;
  const int h  = PHASE ? (bh & 15) : bh;
  const int tid = threadIdx.x;
  const int w = tid >> 6;
  const int lane = tid & 63;
  const int l15 = lane & 15, g = lane >> 4;

  const int t1 = (q0 >= 128) ? max(128, (q0 - 103) & ~31) : 128;
  const int nt1 = (q0 + 64 > t1) ? (q0 + 64 - t1) / 32 : 0;
  const int ntiles = 4 + nt1;
  const int nfrags = ntiles * 2;             // <= 20

  __shared__ float redm[4][64];
  __shared__ float reds[4][64];
  __shared__ __align__(16) char plds[(PHASE ? 64 * PLDS_STRIDE : 16)];

  const size_t qkbase = (size_t)bh * S_LEN;

  bf16x8 af[4][4];
  #pragma unroll
  for (int mi = 0; mi < 4; mi++)
    #pragma unroll
    for (int dt = 0; dt < 4; dt++)
      af[mi][dt] = *(const bf16x8*)(Qb + (qkbase + q0 + mi*16 + l15)*HDIM + dt*32 + g*8);

  int kb[5];
  #pragma unroll
  for (int fi = 0; fi < 5; fi++) {
    int f = w + fi*4;
    if (f < nfrags) {
      int ti = f >> 1;
      int kt = (ti < 4) ? ti*32 : t1 + (ti-4)*32;
      kb[fi] = kt + (f & 1)*16;
    } else kb[fi] = -1;
  }

  f32x4 sacc[4][5];
  #pragma unroll
  for (int mi = 0; mi < 4; mi++)
    #pragma unroll
    for (int fi = 0; fi < 5; fi++)
      #pragma unroll
      for (int r = 0; r < 4; r++) sacc[mi][fi][r] = 0.f;

  #pragma unroll
  for (int fi = 0; fi < 5; fi++) {
    if (kb[fi] < 0) continue;
    #pragma unroll
    for (int dt = 0; dt < 4; dt++) {
      bf16x8 bfr = *(const bf16x8*)(Kb + (qkbase + kb[fi] + l15)*HDIM + dt*32 + g*8);
      #pragma unroll
      for (int mi = 0; mi < 4; mi++)
        sacc[mi][fi] = __builtin_amdgcn_mfma_f32_16x16x32_bf16(af[mi][dt], bfr, sacc[mi][fi], 0, 0, 0);
    }
  }

  #pragma unroll
  for (int fi = 0; fi < 5; fi++) {
    if (kb[fi] < 0) continue;
    int kcol = kb[fi] + l15;
    float amv = amask[b * S_LEN + kcol];
    #pragma unroll
    for (int mi = 0; mi < 4; mi++)
      #pragma unroll
      for (int r = 0; r < 4; r++) {
        int q = q0 + mi*16 + g*4 + r;
        bool ok = (kcol <= q) && ((kcol < SB) || (kcol + RB >= q));
        sacc[mi][fi][r] = ok ? sacc[mi][fi][r] * 0.08838834764831845f + amv : -3.0e38f;
      }
  }

  float rmax[4][4];
  #pragma unroll
  for (int mi = 0; mi < 4; mi++)
    #pragma unroll
    for (int r = 0; r < 4; r++) {
      float m = -3.4e38f;
      #pragma unroll
      for (int fi = 0; fi < 5; fi++)
        if (kb[fi] >= 0) m = fmaxf(m, sacc[mi][fi][r]);
      #pragma unroll
      for (int d = 1; d < 16; d <<= 1) m = fmaxf(m, __shfl_xor(m, d));
      rmax[mi][r] = m;
    }
  if (l15 == 0)
    #pragma unroll
    for (int mi = 0; mi < 4; mi++)
      #pragma unroll
      for (int r = 0; r < 4; r++) redm[w][mi*16 + g*4 + r] = rmax[mi][r];
  __syncthreads();
  #pragma unroll
  for (int mi = 0; mi < 4; mi++)
    #pragma unroll
    for (int r = 0; r < 4; r++) {
      int q = mi*16 + g*4 + r;
      rmax[mi][r] = fmaxf(fmaxf(redm[0][q], redm[1][q]), fmaxf(redm[2][q], redm[3][q]));
    }

  float rsum[4][4];
  #pragma unroll
  for (int mi = 0; mi < 4; mi++)
    #pragma unroll
    for (int r = 0; r < 4; r++) rsum[mi][r] = 0.f;
  #pragma unroll
  for (int fi = 0; fi < 5; fi++) {
    if (kb[fi] < 0) continue;
    #pragma unroll
    for (int mi = 0; mi < 4; mi++)
      #pragma unroll
      for (int r = 0; r < 4; r++) {
        float e = __expf(sacc[mi][fi][r] - rmax[mi][r]);
        sacc[mi][fi][r] = e;
        rsum[mi][r] += e;
      }
  }
  #pragma unroll
  for (int mi = 0; mi < 4; mi++)
    #pragma unroll
    for (int r = 0; r < 4; r++) {
      float s = rsum[mi][r];
      #pragma unroll
      for (int d = 1; d < 16; d <<= 1) s += __shfl_xor(s, d);
      rsum[mi][r] = s;
    }
  if (l15 == 0)
    #pragma unroll
    for (int mi = 0; mi < 4; mi++)
      #pragma unroll
      for (int r = 0; r < 4; r++) reds[w][mi*16 + g*4 + r] = rsum[mi][r];
  __syncthreads();
  float inv[4][4];
  #pragma unroll
  for (int mi = 0; mi < 4; mi++)
    #pragma unroll
    for (int r = 0; r < 4; r++) {
      int q = mi*16 + g*4 + r;
      inv[mi][r] = 1.0f / (reds[0][q] + reds[1][q] + reds[2][q] + reds[3][q]);
    }

  if constexpr (PHASE == 0) {
    #pragma unroll
    for (int fi = 0; fi < 5; fi++) {
      if (kb[fi] < 0) continue;
      int kcol = kb[fi] + l15;
      #pragma unroll
      for (int mi = 0; mi < 4; mi++)
        #pragma unroll
        for (int r = 0; r < 4; r++) {
          int q = q0 + mi*16 + g*4 + r;
          float p = sacc[mi][fi][r] * inv[mi][r];
          if (kcol < 128)
            Pstart[((size_t)h*128 + kcol)*S_LEN + q] = p;
          if (kcol >= SB && kcol < 1023 && kcol <= q && q - kcol <= RB)
            PbT[((size_t)h*920 + (kcol - SB))*104 + (q - kcol)] = p;
        }
    }
  } else {
    #pragma unroll
    for (int fi = 0; fi < 5; fi++) {
      if (kb[fi] < 0) continue;
      int cc = (w + fi*4)*16 + l15;
      #pragma unroll
      for (int mi = 0; mi < 4; mi++)
        #pragma unroll
        for (int r = 0; r < 4; r++) {
          int qs = mi*16 + g*4 + r;
          *(__hip_bfloat16*)(plds + qs*PLDS_STRIDE + cc*2) =
              __float2bfloat16(sacc[mi][fi][r] * inv[mi][r]);
        }
    }
    __syncthreads();
    f32x4 pacc[4][2];
    #pragma unroll
    for (int mi = 0; mi < 4; mi++)
      #pragma unroll
      for (int nj = 0; nj < 2; nj++)
        #pragma unroll
        for (int r = 0; r < 4; r++) pacc[mi][nj][r] = 0.f;
    for (int ti = 0; ti < ntiles; ti++) {
      int kt = (ti < 4) ? ti*32 : t1 + (ti-4)*32;
      int cb = ti*32;
      bf16x8 pa[4];
      #pragma unroll
      for (int mi = 0; mi < 4; mi++)
        pa[mi] = lds_load8(plds + (mi*16 + l15)*PLDS_STRIDE + (cb + g*8)*2);
      #pragma unroll
      for (int nj = 0; nj < 2; nj++) {
        int d = w*32 + nj*16 + l15;
        bf16x8 vb = *(const bf16x8*)(Vt + ((size_t)bh*HDIM + d)*S_LEN + kt + g*8);
        #pragma unroll
        for (int mi = 0; mi < 4; mi++)
          pacc[mi][nj] = __builtin_amdgcn_mfma_f32_16x16x32_bf16(pa[mi], vb, pacc[mi][nj], 0, 0, 0);
      }
    }
    #pragma unroll
    for (int mi = 0; mi < 4; mi++)
      #pragma unroll
      for (int nj = 0; nj < 2; nj++)
        #pragma unroll
        for (int r = 0; r < 4; r++) {
          int q = q0 + mi*16 + g*4 + r;
          int d = w*32 + nj*16 + l15;
          Aout[((size_t)b*S_LEN + q)*HID + h*HDIM + d] = __float2bfloat16(pacc[mi][nj][r]);
        }
  }
}

// ---------------- stats: sstart + band merged (wave-per-column prefix scans) ----------------
__global__ __launch_bounds__(256) void k_scans(const float* __restrict__ Pstart,
                                               const float* __restrict__ PbT,
                                               float* __restrict__ Sstart,
                                               float* __restrict__ Band) {
  int lane = threadIdx.x & 63;
  if (blockIdx.x < 412) {
    int wid = blockIdx.x*4 + (threadIdx.x >> 6);
    if (wid >= NHEAD * SB) return;
    int h = wid / SB, k = wid % SB;
    const float* col = Pstart + ((size_t)h*128 + k)*S_LEN;
    float carry = 0.f;
    for (int seg = 0; seg < 16; seg++) {
      int q = seg*64 + lane;
      float v = col[q];
      #pragma unroll
      for (int d = 1; d < 64; d <<= 1) {
        float u = __shfl_up(v, d);
        if (lane >= d) v += u;
      }
      float tot = carry + v;
      int t = q + 1;
      if (t >= TMIN && t < S_LEN)
        Sstart[((size_t)h*SB + k)*NT + (t - TMIN)] = tot;
      carry += __shfl(v, 63);
    }
  } else {
    int wid = (blockIdx.x - 412)*4 + (threadIdx.x >> 6);
    if (wid >= NHEAD * 920) return;
    int h = wid / 920, kk = wid % 920;
    int k = kk + SB;
    const float* col = PbT + ((size_t)h*920 + kk)*104;
    float carry = 0.f;
    #pragma unroll
    for (int seg = 0; seg < 2; seg++) {
      int i = seg*64 + lane;
      bool valid = (i <= 102) && (k + i <= 1022);
      float v = valid ? col[i] : 0.f;
      #pragma unroll
      for (int d = 1; d < 64; d <<= 1) {
        float u = __shfl_up(v, d);
        if (lane >= d) v += u;
      }
      float tot = carry + v;
      int t = k + i + 1;
      if (valid && t >= TMIN && t < S_LEN) {
        int j = 102 - i;
        Band[((size_t)h*S_LEN + t)*SB + j] = tot;
      }
      carry += __shfl(v, 63);
    }
  }
}

// ---------------- prob + threefry bernoulli ----------------
__global__ __launch_bounds__(64) void k_mask(const float* __restrict__ Sstart,
    const float* __restrict__ Band, float* __restrict__ Mask) {
  const int t = TMIN + blockIdx.x;
  const int lane = threadIdx.x;
  const int h = lane >> 2, j = lane & 3;
  const float* bb = Band + ((size_t)h*S_LEN + t)*SB;
  float mx = -3.4e38f;
  for (int i = j; i < SB; i += 4)
    mx = fmaxf(mx, Sstart[((size_t)h*SB + i)*NT + (t - TMIN)]);
  for (int i = j; i < RB; i += 4) mx = fmaxf(mx, bb[i]);
  mx = fmaxf(mx, __shfl_xor(mx, 1));
  mx = fmaxf(mx, __shfl_xor(mx, 2));
  if (j == 0) {
    float prob = bb[0] / mx;
    prob = fminf(fmaxf(prob, 0.f), 1.f);
    unsigned a0, a1, b0, b1;
    tf2x32(0u, 42u, 0u, (unsigned)t, a0, a1);
    tf2x32(a0, a1, 0u, (unsigned)h, b0, b1);
    float u = tfu(b0 ^ b1);
    Mask[t*NHEAD + h] = (u < prob) ? 1.f : 0.f;
  }
}

// ---------------- fused CAM scan + vupdate -> Vup bf16 [bh][p][d] ----------------
__global__ __launch_bounds__(64) void k_scan(const float* __restrict__ Vf,
    const float* __restrict__ Mask, __hip_bfloat16* __restrict__ Vup) {
  const int blk = blockIdx.x;       // 0..127
  const int bh = blk >> 1, dc = blk & 1;
  const int h = bh & 15;
  const int lane = threadIdx.x;
  const int col = dc*64 + lane;
  __shared__ float ring[RB * 64];   // w ring
  __shared__ float pring[RB * 64];  // P ring
  __shared__ float marr[NT];
  for (int i = lane; i < NT; i += 64) marr[i] = Mask[(TMIN + i)*NHEAD + h];
  __syncthreads();
  const size_t vbase = (size_t)bh * S_LEN * HDIM + col;
  const size_t obase = (size_t)bh * S_LEN * HDIM + col;
  #pragma unroll 4
  for (int p = 0; p <= 103; p++)
    Vup[obase + (size_t)p * HDIM] = __float2bfloat16(Vf[vbase + (size_t)p * HDIM]);

  float S = 0.f, P = 0.f;
  float cur[8], nxt[8];
  #pragma unroll
  for (int u = 0; u < 8; u++)
    cur[u] = Vf[vbase + (size_t)(TMIN - RB + u) * HDIM];
  for (int t0 = TMIN; t0 < S_LEN; t0 += 8) {
    #pragma unroll
    for (int u = 0; u < 8; u++) {
      int t = t0 + 8 + u;
      if (t < S_LEN + 8) nxt[u] = Vf[vbase + (size_t)min(t - RB, S_LEN - 1) * HDIM];
    }
    float olds[8], plo[8];
    #pragma unroll
    for (int u = 0; u < 8; u++) {
      int t = t0 + u;
      olds[u] = (t >= TMIN + RB) ? ring[(t % RB)*64 + lane] : 0.f;
      plo[u]  = (t >= TMIN + RB) ? pring[(t % RB)*64 + lane] : 0.f;  // = P(t-103)
    }
    #pragma unroll
    for (int u = 0; u < 8; u++) {
      int t = t0 + u;
      float a = fmaf(S, (1.f/103.f), cur[u]);
      float w = marr[t - TMIN] * a;
      P += w;
      float vnext = (u < 7) ? cur[u + 1] : nxt[0];
      float Plo = (t <= 308) ? 0.f : plo[u];
      Vup[obase + (size_t)(t - 102) * HDIM] = __float2bfloat16(vnext + (P - Plo) * (1.f/103.f));
      pring[(t % RB)*64 + lane] = P;
      ring[(t % RB)*64 + lane] = w;
      S += w - olds[u];
      cur[u] = nxt[u];
    }
  }
  const float Pfin = P;
  for (int p = 922; p <= 1023; p++) {
    float Plo = pring[((p - 1) % RB)*64 + lane];
    float v = Vf[vbase + (size_t)p * HDIM];
    Vup[obase + (size_t)p * HDIM] = __float2bfloat16(v + (Pfin - Plo) * (1.f/103.f));
  }
}

extern "C" void kernel_launch(void* const* d_in, const int* in_sizes, int n_in,
                              void* d_out, int out_size, void* d_ws, size_t ws_size,
                              hipStream_t stream) {
  const float* hs    = (const float*)d_in[0];
  const float* amask = (const float*)d_in[1];
  const int*   pid   = (const int*)d_in[2];
  const float* Wqkv  = (const float*)d_in[3];
  const float* bqkv  = (const float*)d_in[4];
  const float* Wd    = (const float*)d_in[5];
  const float* bd    = (const float*)d_in[6];
  float* Out = (float*)d_out;

  char* ws = (char*)d_ws;
  size_t off = 0;
  auto alloc = [&](size_t bytes) {
    char* p = ws + off;
    off += (bytes + 255) & ~(size_t)255;
    return p;
  };
  __hip_bfloat16* Xb     = (__hip_bfloat16*)alloc(16777216);  // 4096x2048 bf16
  __hip_bfloat16* WqkvT  = (__hip_bfloat16*)alloc(25165824);  // 6144x2048 bf16
  __hip_bfloat16* WdT    = (__hip_bfloat16*)alloc(8388608);   // 2048x2048 bf16
  __hip_bfloat16* Qb     = (__hip_bfloat16*)alloc(16777216);  // (4,16,1024,128) bf16
  __hip_bfloat16* Kb     = (__hip_bfloat16*)alloc(16777216);
  float*          Vf     = (float*)alloc(33554432);           // (4,16,1024,128) f32
  __hip_bfloat16* Vup    = (__hip_bfloat16*)alloc(16777216);  // (64,1024,128) bf16
  __hip_bfloat16* Vt     = (__hip_bfloat16*)alloc(16777216);  // (64,128,1024) bf16
  float*          Pstart = (float*)alloc(8388608);            // (16,128,1024) f32
  float*          PbT    = (float*)alloc(6123520);            // (16,920,104) f32
  float*          Sstart = (float*)alloc(5392256);            // (16,103,818) f32
  float*          Band   = (float*)alloc(6750208);            // (16,1024,103) f32
  float*          Mask   = (float*)alloc(65536);              // (1024,16) f32
  __hip_bfloat16* Aout   = (__hip_bfloat16*)alloc(16777216);  // 4096x2048 bf16

  k_prep<<<24576, 256, 0, stream>>>(hs, Wqkv, Wd, Xb, WqkvT, WdT);
  k_gemm_qkv<<<dim3(32, 48), 256, 0, stream>>>(Xb, WqkvT, bqkv, pid, Qb, Kb, Vf);
  k_flash<0><<<dim3(16, 16), 256, 0, stream>>>(Qb, Kb, nullptr, amask, Pstart, PbT, nullptr);
  k_scans<<<4092, 256, 0, stream>>>(Pstart, PbT, Sstart, Band);
  k_mask<<<818, 64, 0, stream>>>(Sstart, Band, Mask);
  k_scan<<<128, 64, 0, stream>>>(Vf, Mask, Vup);
  k_vtrans2<<<dim3(32, 4, 64), dim3(32, 8), 0, stream>>>(Vup, Vt);
  k_flash<1><<<dim3(16, 64), 256, 0, stream>>>(Qb, Kb, Vt, amask, nullptr, nullptr, Aout);
  k_gemm_out<<<dim3(32, 16), 256, 0, stream>>>(Aout, WdT, bd, Out);
}

// Round 13
// 416.199 us; speedup vs baseline: 1.0689x; 1.0140x over previous
//
#include <hip/hip_runtime.h>
#include <hip/hip_bf16.h>

// GPTNeoXAttention + CAM mask pipeline, MI355X (gfx950)
// B=4 S=1024 HID=2048 NH=16 HD=128 ROT=32, sb=rb=103
//
// R13: R12 + BK=64 double-buffer-in-one-barrier GEMM core: stage two 32-K
// subtiles into disjoint LDS regions (32 KB), ONE barrier pair per 64-K
// (halves the s_waitcnt vmcnt(0) barrier drains — the known ~20% stall of
// this structure). Same layout/addressing as the proven R2 core.

#define S_LEN 1024
#define NHEAD 16
#define HDIM  128
#define HID   2048
#define SB    103
#define RB    103
#define TMIN  206
#define NT    818

typedef __bf16 bf16x8 __attribute__((ext_vector_type(8)));
typedef __bf16 bf16x4 __attribute__((ext_vector_type(4)));
typedef float  f32x4  __attribute__((ext_vector_type(4)));

#define PLDS_STRIDE 648

// ---------------- threefry2x32 (JAX-compatible) ----------------
__device__ __forceinline__ void tf2x32(unsigned k0, unsigned k1,
                                       unsigned x0, unsigned x1,
                                       unsigned& o0, unsigned& o1) {
  unsigned ks2 = k0 ^ k1 ^ 0x1BD11BDAu;
  x0 += k0; x1 += k1;
#define TFR(r) { x0 += x1; x1 = (x1 << r) | (x1 >> (32 - r)); x1 ^= x0; }
  TFR(13) TFR(15) TFR(26) TFR(6)   x0 += k1;  x1 += ks2 + 1u;
  TFR(17) TFR(29) TFR(16) TFR(24)  x0 += ks2; x1 += k0 + 2u;
  TFR(13) TFR(15) TFR(26) TFR(6)   x0 += k0;  x1 += k1 + 3u;
  TFR(17) TFR(29) TFR(16) TFR(24)  x0 += k1;  x1 += ks2 + 4u;
  TFR(13) TFR(15) TFR(26) TFR(6)   x0 += ks2; x1 += k0 + 5u;
#undef TFR
  o0 = x0; o1 = x1;
}
__device__ __forceinline__ float tfu(unsigned b) {
  return __builtin_bit_cast(float, (b >> 9) | 0x3f800000u) - 1.0f;
}

// ---------------- fused preprocessing: cast X + transpose Wqkv + transpose Wd ----------------
__global__ __launch_bounds__(256) void k_prep(const float* __restrict__ hs,
    const float* __restrict__ Wqkv, const float* __restrict__ Wd,
    __hip_bfloat16* __restrict__ Xb, __hip_bfloat16* __restrict__ WqkvT,
    __hip_bfloat16* __restrict__ WdT) {
  __shared__ float tile[32][33];
  const int bid = blockIdx.x;
  const int tid = threadIdx.x;
  if (bid < 8192) {
    int i = bid * 256 + tid;
    float4 v = ((const float4*)hs)[i];
    __hip_bfloat162 lo = __float22bfloat162_rn(make_float2(v.x, v.y));
    __hip_bfloat162 hi = __float22bfloat162_rn(make_float2(v.z, v.w));
    ((__hip_bfloat162*)Xb)[2*i]   = lo;
    ((__hip_bfloat162*)Xb)[2*i+1] = hi;
    return;
  }
  const float* W; __hip_bfloat16* Wt; int N, n0, k0;
  if (bid < 20480) {
    int b2 = bid - 8192;
    W = Wqkv; Wt = WqkvT; N = 6144;
    n0 = (b2 % 192) * 32; k0 = (b2 / 192) * 32;
  } else {
    int b3 = bid - 20480;
    W = Wd; Wt = WdT; N = 2048;
    n0 = (b3 % 64) * 32; k0 = (b3 / 64) * 32;
  }
  const int tx = tid & 31, ty = tid >> 5;
  #pragma unroll
  for (int i = 0; i < 32; i += 8)
    tile[ty + i][tx] = W[(size_t)(k0 + ty + i) * N + n0 + tx];
  __syncthreads();
  #pragma unroll
  for (int i = 0; i < 32; i += 8)
    Wt[(size_t)(n0 + ty + i) * 2048 + k0 + tx] = __float2bfloat16(tile[tx][ty + i]);
}

// ---------------- pure bf16 transpose: Vup [bh][k][d] -> Vt [bh][d][k] ----------------
__global__ __launch_bounds__(256) void k_vtrans2(const __hip_bfloat16* __restrict__ Vup,
                                                 __hip_bfloat16* __restrict__ Vt) {
  __shared__ unsigned short tile[32][33];
  int k0 = blockIdx.x * 32, d0 = blockIdx.y * 32, bh = blockIdx.z;
  int tx = threadIdx.x, ty = threadIdx.y;
  const unsigned short* src = (const unsigned short*)Vup;
  unsigned short* dst = (unsigned short*)Vt;
  #pragma unroll
  for (int i = 0; i < 32; i += 8)
    tile[ty + i][tx] = src[((size_t)bh * S_LEN + (k0 + ty + i)) * HDIM + d0 + tx];
  __syncthreads();
  #pragma unroll
  for (int i = 0; i < 32; i += 8)
    dst[((size_t)bh * HDIM + (d0 + ty + i)) * S_LEN + k0 + tx] = tile[tx][ty + i];
}

// ---------------- 128x128 bf16 MFMA GEMM core, BK=64 single-barrier-pair ----------------
// LDS 32 KB: A0 @0, B0 @8192, A1 @16384, B1 @24576 (each 8 KB, 64-B row stride).
__device__ __forceinline__ void gemm128(const char* __restrict__ A, const char* __restrict__ Bt,
                                        int K, long rowA0, long rowB0, char* lds,
                                        f32x4 (&acc)[4][4]) {
  const int tid  = threadIdx.x;
  const int lane = tid & 63;
  const int wave = tid >> 6;
  const int wm = wave >> 1, wn = wave & 1;
  const int l4  = lane >> 2;
  const int lkb = (lane & 3) * 16;
  const int rlo = lane & 15;
  const int khi = (lane >> 4) * 16;
  const long strA = (long)K * 2;
  for (int k0 = 0; k0 < K; k0 += 64) {
    // stage both 32-K halves (8 loads/thread in flight), then one barrier
    #pragma unroll
    for (int half = 0; half < 2; half++) {
      const long kof = (long)(k0 + half * 32) * 2;
      char* ldsA = lds + half * 16384;
      char* ldsB = lds + half * 16384 + 8192;
      #pragma unroll
      for (int q = 0; q < 2; q++) {
        long ra = rowA0 + wave*32 + q*16 + l4;
        const char* ga = A + ra*strA + kof + lkb;
        __builtin_amdgcn_global_load_lds((const __attribute__((address_space(1))) void*)ga,
            (__attribute__((address_space(3))) void*)(ldsA + wave*2048 + q*1024), 16, 0, 0);
        long rbn = rowB0 + wave*32 + q*16 + l4;
        const char* gb = Bt + rbn*strA + kof + lkb;
        __builtin_amdgcn_global_load_lds((const __attribute__((address_space(1))) void*)gb,
            (__attribute__((address_space(3))) void*)(ldsB + wave*2048 + q*1024), 16, 0, 0);
      }
    }
    __syncthreads();
    #pragma unroll
    for (int half = 0; half < 2; half++) {
      const char* ldsA = lds + half * 16384;
      const char* ldsB = lds + half * 16384 + 8192;
      bf16x8 af[4], bfr[4];
      #pragma unroll
      for (int mf = 0; mf < 4; mf++)
        af[mf] = *(const bf16x8*)(ldsA + (wm*64 + mf*16 + rlo)*64 + khi);
      #pragma unroll
      for (int nf = 0; nf < 4; nf++)
        bfr[nf] = *(const bf16x8*)(ldsB + (wn*64 + nf*16 + rlo)*64 + khi);
      #pragma unroll
      for (int mf = 0; mf < 4; mf++)
        #pragma unroll
        for (int nf = 0; nf < 4; nf++)
          acc[mf][nf] = __builtin_amdgcn_mfma_f32_16x16x32_bf16(af[mf], bfr[nf], acc[mf][nf], 0, 0, 0);
    }
    __syncthreads();
  }
}

// ---------------- GEMM qkv + bias + RoPE + scatter ----------------
__global__ __launch_bounds__(256, 3) void k_gemm_qkv(const __hip_bfloat16* __restrict__ Xb,
    const __hip_bfloat16* __restrict__ WqkvT, const float* __restrict__ bqkv,
    const int* __restrict__ pid,
    __hip_bfloat16* __restrict__ Qb, __hip_bfloat16* __restrict__ Kb, float* __restrict__ Vf) {
  __shared__ __align__(16) char lds[32768];
  f32x4 acc[4][4];
  #pragma unroll
  for (int m = 0; m < 4; m++)
    #pragma unroll
    for (int n = 0; n < 4; n++)
      #pragma unroll
      for (int r = 0; r < 4; r++) acc[m][n][r] = 0.f;
  // XCD-bijective swizzle: nwg = 1536 = 8 * 192
  int flat = blockIdx.y * 32 + blockIdx.x;
  int swz = (flat & 7) * 192 + (flat >> 3);
  int bm = swz & 31, bn = swz >> 5;
  gemm128((const char*)Xb, (const char*)WqkvT, HID, (long)bm*128, (long)bn*128, lds, acc);
  const int lane = threadIdx.x & 63, wave = threadIdx.x >> 6;
  const int wm = wave >> 1, wn = wave & 1;
  const int colbase = bn*128 + wn*64;
  const int rowbase = bm*128 + wm*64 + (lane >> 4) * 4;
  // bias
  #pragma unroll
  for (int nf = 0; nf < 4; nf++) {
    int col = colbase + nf*16 + (lane & 15);
    float bias = bqkv[col];
    #pragma unroll
    for (int mf = 0; mf < 4; mf++)
      #pragma unroll
      for (int r = 0; r < 4; r++) acc[mf][nf][r] += bias;
  }
  // RoPE: pair (i, i+16) in frags nf=0,1 at same lane iff colbase%384 in {0,128}
  const int jb = colbase % 384;
  if (jb == 0 || jb == 128) {
    const int i = lane & 15;
    const float invf = exp2f(-(float)i * 0.8304820237218406f); // 10000^(-i/16)
    #pragma unroll
    for (int mf = 0; mf < 4; mf++) {
      #pragma unroll
      for (int r = 0; r < 4; r++) {
        int row = rowbase + mf*16 + r;
        int b = row >> 10, s = row & 1023;
        float th = (float)pid[b * S_LEN + s] * invf;
        float sn, cs;
        sincosf(th, &sn, &cs);
        float x1 = acc[mf][0][r], x2 = acc[mf][1][r];
        acc[mf][0][r] = x1*cs - x2*sn;
        acc[mf][1][r] = x2*cs + x1*sn;
      }
    }
  }
  // scatter
  #pragma unroll
  for (int mf = 0; mf < 4; mf++) {
    #pragma unroll
    for (int nf = 0; nf < 4; nf++) {
      int col = colbase + nf*16 + (lane & 15);
      int h = col / 384, j = col % 384;
      #pragma unroll
      for (int r = 0; r < 4; r++) {
        int row = rowbase + mf*16 + r;
        int b = row >> 10, s = row & 1023;
        size_t base = ((size_t)(b*NHEAD + h)*S_LEN + s)*HDIM;
        float v = acc[mf][nf][r];
        if (j < 128)      Qb[base + j]       = __float2bfloat16(v);
        else if (j < 256) Kb[base + j - 128] = __float2bfloat16(v);
        else              Vf[base + j - 256] = v;
      }
    }
  }
}

// ---------------- GEMM out-proj + bias ----------------
__global__ __launch_bounds__(256, 3) void k_gemm_out(const __hip_bfloat16* __restrict__ Ab,
    const __hip_bfloat16* __restrict__ WdT, const float* __restrict__ bd,
    float* __restrict__ Out) {
  __shared__ __align__(16) char lds[32768];
  f32x4 acc[4][4];
  #pragma unroll
  for (int m = 0; m < 4; m++)
    #pragma unroll
    for (int n = 0; n < 4; n++)
      #pragma unroll
      for (int r = 0; r < 4; r++) acc[m][n][r] = 0.f;
  // XCD-bijective swizzle: nwg = 512 = 8 * 64
  int flat = blockIdx.y * 32 + blockIdx.x;
  int swz = (flat & 7) * 64 + (flat >> 3);
  int bm = swz & 31, bn = swz >> 5;
  gemm128((const char*)Ab, (const char*)WdT, HID, (long)bm*128, (long)bn*128, lds, acc);
  const int lane = threadIdx.x & 63, wave = threadIdx.x >> 6;
  const int wm = wave >> 1, wn = wave & 1;
  const int colbase = bn*128 + wn*64;
  const int rowbase = bm*128 + wm*64 + (lane >> 4) * 4;
  #pragma unroll
  for (int nf = 0; nf < 4; nf++) {
    int col = colbase + nf*16 + (lane & 15);
    float bias = bd[col];
    #pragma unroll
    for (int mf = 0; mf < 4; mf++)
      #pragma unroll
      for (int r = 0; r < 4; r++) {
        int row = rowbase + mf*16 + r;
        Out[(size_t)row * HID + col] = acc[mf][nf][r] + bias;
      }
  }
}

// ---------------- banded flash attention (R5 structure + occupancy cap) ----------------
__device__ __forceinline__ bf16x8 lds_load8(const char* p) {
  bf16x4 lo = *(const bf16x4*)p;
  bf16x4 hi = *(const bf16x4*)(p + 8);
  bf16x8 v;
  v[0]=lo[0]; v[1]=lo[1]; v[2]=lo[2]; v[3]=lo[3];
  v[4]=hi[0]; v[5]=hi[1]; v[6]=hi[2]; v[7]=hi[3];
  return v;
}

template<int PHASE>
__global__ __launch_bounds__(256, 3) void k_flash(const __hip_bfloat16* __restrict__ Qb,
    const __hip_bfloat16* __restrict__ Kb, const __hip_bfloat16* __restrict__ Vt,
    const float* __restrict__ amask,
    float* __restrict__ Pstart, float* __restrict__ PbT,
    __hip_bfloat16* __restrict__ Aout) {
  const int q0 = blockIdx.x * 64;
  const int bh = blockIdx.y;                 // PHASE0: h, PHASE1: b*16+h
  const int b  = PHASE ? (bh >> 4) : 0;
  const int h  = PHASE ? (bh & 15) : bh;
  const int tid = threadIdx.x;
  const int w = tid >> 6;
  const int lane = tid & 63;
  const int l15 = lane & 15, g = lane >> 4;

  const int t1 = (q0 >= 128) ? max(128, (q0 - 103) & ~31) : 128;
  const int nt1 = (q0 + 64 > t1) ? (q0 + 64 - t1) / 32 : 0;
  const int ntiles = 4 + nt1;
  const int nfrags = ntiles * 2;             // <= 20

  __shared__ float redm[4][64];
  __shared__ float reds[4][64];
  __shared__ __align__(16) char plds[(PHASE ? 64 * PLDS_STRIDE : 16)];

  const size_t qkbase = (size_t)bh * S_LEN;

  bf16x8 af[4][4];
  #pragma unroll
  for (int mi = 0; mi < 4; mi++)
    #pragma unroll
    for (int dt = 0; dt < 4; dt++)
      af[mi][dt] = *(const bf16x8*)(Qb + (qkbase + q0 + mi*16 + l15)*HDIM + dt*32 + g*8);

  int kb[5];
  #pragma unroll
  for (int fi = 0; fi < 5; fi++) {
    int f = w + fi*4;
    if (f < nfrags) {
      int ti = f >> 1;
      int kt = (ti < 4) ? ti*32 : t1 + (ti-4)*32;
      kb[fi] = kt + (f & 1)*16;
    } else kb[fi] = -1;
  }

  f32x4 sacc[4][5];
  #pragma unroll
  for (int mi = 0; mi < 4; mi++)
    #pragma unroll
    for (int fi = 0; fi < 5; fi++)
      #pragma unroll
      for (int r = 0; r < 4; r++) sacc[mi][fi][r] = 0.f;

  #pragma unroll
  for (int fi = 0; fi < 5; fi++) {
    if (kb[fi] < 0) continue;
    #pragma unroll
    for (int dt = 0; dt < 4; dt++) {
      bf16x8 bfr = *(const bf16x8*)(Kb + (qkbase + kb[fi] + l15)*HDIM + dt*32 + g*8);
      #pragma unroll
      for (int mi = 0; mi < 4; mi++)
        sacc[mi][fi] = __builtin_amdgcn_mfma_f32_16x16x32_bf16(af[mi][dt], bfr, sacc[mi][fi], 0, 0, 0);
    }
  }

  #pragma unroll
  for (int fi = 0; fi < 5; fi++) {
    if (kb[fi] < 0) continue;
    int kcol = kb[fi] + l15;
    float amv = amask[b * S_LEN + kcol];
    #pragma unroll
    for (int mi = 0; mi < 4; mi++)
      #pragma unroll
      for (int r = 0; r < 4; r++) {
        int q = q0 + mi*16 + g*4 + r;
        bool ok = (kcol <= q) && ((kcol < SB) || (kcol + RB >= q));
        sacc[mi][fi][r] = ok ? sacc[mi][fi][r] * 0.08838834764831845f + amv : -3.0e38f;
      }
  }

  float rmax[4][4];
  #pragma unroll
  for (int mi = 0; mi < 4; mi++)
    #pragma unroll
    for (int r = 0; r < 4; r++) {
      float m = -3.4e38f;
      #pragma unroll
      for (int fi = 0; fi < 5; fi++)
        if (kb[fi] >= 0) m = fmaxf(m, sacc[mi][fi][r]);
      #pragma unroll
      for (int d = 1; d < 16; d <<= 1) m = fmaxf(m, __shfl_xor(m, d));
      rmax[mi][r] = m;
    }
  if (l15 == 0)
    #pragma unroll
    for (int mi = 0; mi < 4; mi++)
      #pragma unroll
      for (int r = 0; r < 4; r++) redm[w][mi*16 + g*4 + r] = rmax[mi][r];
  __syncthreads();
  #pragma unroll
  for (int mi = 0; mi < 4; mi++)
    #pragma unroll
    for (int r = 0; r < 4; r++) {
      int q = mi*16 + g*4 + r;
      rmax[mi][r] = fmaxf(fmaxf(redm[0][q], redm[1][q]), fmaxf(redm[2][q], redm[3][q]));
    }

  float rsum[4][4];
  #pragma unroll
  for (int mi = 0; mi < 4; mi++)
    #pragma unroll
    for (int r = 0; r < 4; r++) rsum[mi][r] = 0.f;
  #pragma unroll
  for (int fi = 0; fi < 5; fi++) {
    if (kb[fi] < 0) continue;
    #pragma unroll
    for (int mi = 0; mi < 4; mi++)
      #pragma unroll
      for (int r = 0; r < 4; r++) {
        float e = __expf(sacc[mi][fi][r] - rmax[mi][r]);
        sacc[mi][fi][r] = e;
        rsum[mi][r] += e;
      }
  }
  #pragma unroll
  for (int mi = 0; mi < 4; mi++)
    #pragma unroll
    for (int r = 0; r < 4; r++) {
      float s = rsum[mi][r];
      #pragma unroll
      for (int d = 1; d < 16; d <<= 1) s += __shfl_xor(s, d);
      rsum[mi][r] = s;
    }
  if (l15 == 0)
    #pragma unroll
    for (int mi = 0; mi < 4; mi++)
      #pragma unroll
      for (int r = 0; r < 4; r++) reds[w][mi*16 + g*4 + r] = rsum[mi][r];
  __syncthreads();
  float inv[4][4];
  #pragma unroll
  for (int mi = 0; mi < 4; mi++)
    #pragma unroll
    for (int r = 0; r < 4; r++) {
      int q = mi*16 + g*4 + r;
      inv[mi][r] = 1.0f / (reds[0][q] + reds[1][q] + reds[2][q] + reds[3][q]);
    }

  if constexpr (PHASE == 0) {
    #pragma unroll
    for (int fi = 0; fi < 5; fi++) {
      if (kb[fi] < 0) continue;
      int kcol = kb[fi] + l15;
      #pragma unroll
      for (int mi = 0; mi < 4; mi++)
        #pragma unroll
        for (int r = 0; r < 4; r++) {
          int q = q0 + mi*16 + g*4 + r;
          float p = sacc[mi][fi][r] * inv[mi][r];
          if (kcol < 128)
            Pstart[((size_t)h*128 + kcol)*S_LEN + q] = p;
          if (kcol >= SB && kcol < 1023 && kcol <= q && q - kcol <= RB)
            PbT[((size_t)h*920 + (kcol - SB))*104 + (q - kcol)] = p;
        }
    }
  } else {
    #pragma unroll
    for (int fi = 0; fi < 5; fi++) {
      if (kb[fi] < 0) continue;
      int cc = (w + fi*4)*16 + l15;
      #pragma unroll
      for (int mi = 0; mi < 4; mi++)
        #pragma unroll
        for (int r = 0; r < 4; r++) {
          int qs = mi*16 + g*4 + r;
          *(__hip_bfloat16*)(plds + qs*PLDS_STRIDE + cc*2) =
              __float2bfloat16(sacc[mi][fi][r] * inv[mi][r]);
        }
    }
    __syncthreads();
    f32x4 pacc[4][2];
    #pragma unroll
    for (int mi = 0; mi < 4; mi++)
      #pragma unroll
      for (int nj = 0; nj < 2; nj++)
        #pragma unroll
        for (int r = 0; r < 4; r++) pacc[mi][nj][r] = 0.f;
    for (int ti = 0; ti < ntiles; ti++) {
      int kt = (ti < 4) ? ti*32 : t1 + (ti-4)*32;
      int cb = ti*32;
      bf16x8 pa[4];
      #pragma unroll
      for (int mi = 0; mi < 4; mi++)
        pa[mi] = lds_load8(plds + (mi*16 + l15)*PLDS_STRIDE + (cb + g*8)*2);
      #pragma unroll
      for (int nj = 0; nj < 2; nj++) {
        int d = w*32 + nj*16 + l15;
        bf16x8 vb = *(const bf16x8*)(Vt + ((size_t)bh*HDIM + d)*S_LEN + kt + g*8);
        #pragma unroll
        for (int mi = 0; mi < 4; mi++)
          pacc[mi][nj] = __builtin_amdgcn_mfma_f32_16x16x32_bf16(pa[mi], vb, pacc[mi][nj], 0, 0, 0);
      }
    }
    #pragma unroll
    for (int mi = 0; mi < 4; mi++)
      #pragma unroll
      for (int nj = 0; nj < 2; nj++)
        #pragma unroll
        for (int r = 0; r < 4; r++) {
          int q = q0 + mi*16 + g*4 + r;
          int d = w*32 + nj*16 + l15;
          Aout[((size_t)b*S_LEN + q)*HID + h*HDIM + d] = __float2bfloat16(pacc[mi][nj][r]);
        }
  }
}

// ---------------- stats: sstart + band merged (wave-per-column prefix scans) ----------------
__global__ __launch_bounds__(256) void k_scans(const float* __restrict__ Pstart,
                                               const float* __restrict__ PbT,
                                               float* __restrict__ Sstart,
                                               float* __restrict__ Band) {
  int lane = threadIdx.x & 63;
  if (blockIdx.x < 412) {
    int wid = blockIdx.x*4 + (threadIdx.x >> 6);
    if (wid >= NHEAD * SB) return;
    int h = wid / SB, k = wid % SB;
    const float* col = Pstart + ((size_t)h*128 + k)*S_LEN;
    float carry = 0.f;
    for (int seg = 0; seg < 16; seg++) {
      int q = seg*64 + lane;
      float v = col[q];
      #pragma unroll
      for (int d = 1; d < 64; d <<= 1) {
        float u = __shfl_up(v, d);
        if (lane >= d) v += u;
      }
      float tot = carry + v;
      int t = q + 1;
      if (t >= TMIN && t < S_LEN)
        Sstart[((size_t)h*SB + k)*NT + (t - TMIN)] = tot;
      carry += __shfl(v, 63);
    }
  } else {
    int wid = (blockIdx.x - 412)*4 + (threadIdx.x >> 6);
    if (wid >= NHEAD * 920) return;
    int h = wid / 920, kk = wid % 920;
    int k = kk + SB;
    const float* col = PbT + ((size_t)h*920 + kk)*104;
    float carry = 0.f;
    #pragma unroll
    for (int seg = 0; seg < 2; seg++) {
      int i = seg*64 + lane;
      bool valid = (i <= 102) && (k + i <= 1022);
      float v = valid ? col[i] : 0.f;
      #pragma unroll
      for (int d = 1; d < 64; d <<= 1) {
        float u = __shfl_up(v, d);
        if (lane >= d) v += u;
      }
      float tot = carry + v;
      int t = k + i + 1;
      if (valid && t >= TMIN && t < S_LEN) {
        int j = 102 - i;
        Band[((size_t)h*S_LEN + t)*SB + j] = tot;
      }
      carry += __shfl(v, 63);
    }
  }
}

// ---------------- prob + threefry bernoulli ----------------
__global__ __launch_bounds__(64) void k_mask(const float* __restrict__ Sstart,
    const float* __restrict__ Band, float* __restrict__ Mask) {
  const int t = TMIN + blockIdx.x;
  const int lane = threadIdx.x;
  const int h = lane >> 2, j = lane & 3;
  const float* bb = Band + ((size_t)h*S_LEN + t)*SB;
  float mx = -3.4e38f;
  for (int i = j; i < SB; i += 4)
    mx = fmaxf(mx, Sstart[((size_t)h*SB + i)*NT + (t - TMIN)]);
  for (int i = j; i < RB; i += 4) mx = fmaxf(mx, bb[i]);
  mx = fmaxf(mx, __shfl_xor(mx, 1));
  mx = fmaxf(mx, __shfl_xor(mx, 2));
  if (j == 0) {
    float prob = bb[0] / mx;
    prob = fminf(fmaxf(prob, 0.f), 1.f);
    unsigned a0, a1, b0, b1;
    tf2x32(0u, 42u, 0u, (unsigned)t, a0, a1);
    tf2x32(a0, a1, 0u, (unsigned)h, b0, b1);
    float u = tfu(b0 ^ b1);
    Mask[t*NHEAD + h] = (u < prob) ? 1.f : 0.f;
  }
}

// ---------------- fused CAM scan + vupdate -> Vup bf16 [bh][p][d] ----------------
__global__ __launch_bounds__(64) void k_scan(const float* __restrict__ Vf,
    const float* __restrict__ Mask, __hip_bfloat16* __restrict__ Vup) {
  const int blk = blockIdx.x;       // 0..127
  const int bh = blk >> 1, dc = blk & 1;
  const int h = bh & 15;
  const int lane = threadIdx.x;
  const int col = dc*64 + lane;
  __shared__ float ring[RB * 64];   // w ring
  __shared__ float pring[RB * 64];  // P ring
  __shared__ float marr[NT];
  for (int i = lane; i < NT; i += 64) marr[i] = Mask[(TMIN + i)*NHEAD + h];
  __syncthreads();
  const size_t vbase = (size_t)bh * S_LEN * HDIM + col;
  const size_t obase = (size_t)bh * S_LEN * HDIM + col;
  #pragma unroll 4
  for (int p = 0; p <= 103; p++)
    Vup[obase + (size_t)p * HDIM] = __float2bfloat16(Vf[vbase + (size_t)p * HDIM]);

  float S = 0.f, P = 0.f;
  float cur[8], nxt[8];
  #pragma unroll
  for (int u = 0; u < 8; u++)
    cur[u] = Vf[vbase + (size_t)(TMIN - RB + u) * HDIM];
  for (int t0 = TMIN; t0 < S_LEN; t0 += 8) {
    #pragma unroll
    for (int u = 0; u < 8; u++) {
      int t = t0 + 8 + u;
      if (t < S_LEN + 8) nxt[u] = Vf[vbase + (size_t)min(t - RB, S_LEN - 1) * HDIM];
    }
    float olds[8], plo[8];
    #pragma unroll
    for (int u = 0; u < 8; u++) {
      int t = t0 + u;
      olds[u] = (t >= TMIN + RB) ? ring[(t % RB)*64 + lane] : 0.f;
      plo[u]  = (t >= TMIN + RB) ? pring[(t % RB)*64 + lane] : 0.f;  // = P(t-103)
    }
    #pragma unroll
    for (int u = 0; u < 8; u++) {
      int t = t0 + u;
      float a = fmaf(S, (1.f/103.f), cur[u]);
      float w = marr[t - TMIN] * a;
      P += w;
      float vnext = (u < 7) ? cur[u + 1] : nxt[0];
      float Plo = (t <= 308) ? 0.f : plo[u];
      Vup[obase + (size_t)(t - 102) * HDIM] = __float2bfloat16(vnext + (P - Plo) * (1.f/103.f));
      pring[(t % RB)*64 + lane] = P;
      ring[(t % RB)*64 + lane] = w;
      S += w - olds[u];
      cur[u] = nxt[u];
    }
  }
  const float Pfin = P;
  for (int p = 922; p <= 1023; p++) {
    float Plo = pring[((p - 1) % RB)*64 + lane];
    float v = Vf[vbase + (size_t)p * HDIM];
    Vup[obase + (size_t)p * HDIM] = __float2bfloat16(v + (Pfin - Plo) * (1.f/103.f));
  }
}

extern "C" void kernel_launch(void* const* d_in, const int* in_sizes, int n_in,
                              void* d_out, int out_size, void* d_ws, size_t ws_size,
                              hipStream_t stream) {
  const float* hs    = (const float*)d_in[0];
  const float* amask = (const float*)d_in[1];
  const int*   pid   = (const int*)d_in[2];
  const float* Wqkv  = (const float*)d_in[3];
  const float* bqkv  = (const float*)d_in[4];
  const float* Wd    = (const float*)d_in[5];
  const float* bd    = (const float*)d_in[6];
  float* Out = (float*)d_out;

  char* ws = (char*)d_ws;
  size_t off = 0;
  auto alloc = [&](size_t bytes) {
    char* p = ws + off;
    off += (bytes + 255) & ~(size_t)255;
    return p;
  };
  __hip_bfloat16* Xb     = (__hip_bfloat16*)alloc(16777216);  // 4096x2048 bf16
  __hip_bfloat16* WqkvT  = (__hip_bfloat16*)alloc(25165824);  // 6144x2048 bf16
  __hip_bfloat16* WdT    = (__hip_bfloat16*)alloc(8388608);   // 2048x2048 bf16
  __hip_bfloat16* Qb     = (__hip_bfloat16*)alloc(16777216);  // (4,16,1024,128) bf16
  __hip_bfloat16* Kb     = (__hip_bfloat16*)alloc(16777216);
  float*          Vf     = (float*)alloc(33554432);           // (4,16,1024,128) f32
  __hip_bfloat16* Vup    = (__hip_bfloat16*)alloc(16777216);  // (64,1024,128) bf16
  __hip_bfloat16* Vt     = (__hip_bfloat16*)alloc(16777216);  // (64,128,1024) bf16
  float*          Pstart = (float*)alloc(8388608);            // (16,128,1024) f32
  float*          PbT    = (float*)alloc(6123520);            // (16,920,104) f32
  float*          Sstart = (float*)alloc(5392256);            // (16,103,818) f32
  float*          Band   = (float*)alloc(6750208);            // (16,1024,103) f32
  float*          Mask   = (float*)alloc(65536);              // (1024,16) f32
  __hip_bfloat16* Aout   = (__hip_bfloat16*)alloc(16777216);  // 4096x2048 bf16

  k_prep<<<24576, 256, 0, stream>>>(hs, Wqkv, Wd, Xb, WqkvT, WdT);
  k_gemm_qkv<<<dim3(32, 48), 256, 0, stream>>>(Xb, WqkvT, bqkv, pid, Qb, Kb, Vf);
  k_flash<0><<<dim3(16, 16), 256, 0, stream>>>(Qb, Kb, nullptr, amask, Pstart, PbT, nullptr);
  k_scans<<<4092, 256, 0, stream>>>(Pstart, PbT, Sstart, Band);
  k_mask<<<818, 64, 0, stream>>>(Sstart, Band, Mask);
  k_scan<<<128, 64, 0, stream>>>(Vf, Mask, Vup);
  k_vtrans2<<<dim3(32, 4, 64), dim3(32, 8), 0, stream>>>(Vup, Vt);
  k_flash<1><<<dim3(16, 64), 256, 0, stream>>>(Qb, Kb, Vt, amask, nullptr, nullptr, Aout);
  k_gemm_out<<<dim3(32, 16), 256, 0, stream>>>(Aout, WdT, bd, Out);
}

// Round 14
// 412.851 us; speedup vs baseline: 1.0775x; 1.0081x over previous
//
#include <hip/hip_runtime.h>
#include <hip/hip_bf16.h>

// GPTNeoXAttention + CAM mask pipeline, MI355X (gfx950)
// B=4 S=1024 HID=2048 NH=16 HD=128 ROT=32, sb=rb=103
//
// R14: R13 + L2-blocked block ordering inside each XCD for both GEMMs:
// bm-chunk(8) x bn x bm-within(8) so the A-panel (4 MB) stays L2-resident
// across the bn sweep. Index-only change (bijective), numerics identical.

#define S_LEN 1024
#define NHEAD 16
#define HDIM  128
#define HID   2048
#define SB    103
#define RB    103
#define TMIN  206
#define NT    818

typedef __bf16 bf16x8 __attribute__((ext_vector_type(8)));
typedef __bf16 bf16x4 __attribute__((ext_vector_type(4)));
typedef float  f32x4  __attribute__((ext_vector_type(4)));

#define PLDS_STRIDE 648

// ---------------- threefry2x32 (JAX-compatible) ----------------
__device__ __forceinline__ void tf2x32(unsigned k0, unsigned k1,
                                       unsigned x0, unsigned x1,
                                       unsigned& o0, unsigned& o1) {
  unsigned ks2 = k0 ^ k1 ^ 0x1BD11BDAu;
  x0 += k0; x1 += k1;
#define TFR(r) { x0 += x1; x1 = (x1 << r) | (x1 >> (32 - r)); x1 ^= x0; }
  TFR(13) TFR(15) TFR(26) TFR(6)   x0 += k1;  x1 += ks2 + 1u;
  TFR(17) TFR(29) TFR(16) TFR(24)  x0 += ks2; x1 += k0 + 2u;
  TFR(13) TFR(15) TFR(26) TFR(6)   x0 += k0;  x1 += k1 + 3u;
  TFR(17) TFR(29) TFR(16) TFR(24)  x0 += k1;  x1 += ks2 + 4u;
  TFR(13) TFR(15) TFR(26) TFR(6)   x0 += ks2; x1 += k0 + 5u;
#undef TFR
  o0 = x0; o1 = x1;
}
__device__ __forceinline__ float tfu(unsigned b) {
  return __builtin_bit_cast(float, (b >> 9) | 0x3f800000u) - 1.0f;
}

// ---------------- fused preprocessing: cast X + transpose Wqkv + transpose Wd ----------------
__global__ __launch_bounds__(256) void k_prep(const float* __restrict__ hs,
    const float* __restrict__ Wqkv, const float* __restrict__ Wd,
    __hip_bfloat16* __restrict__ Xb, __hip_bfloat16* __restrict__ WqkvT,
    __hip_bfloat16* __restrict__ WdT) {
  __shared__ float tile[32][33];
  const int bid = blockIdx.x;
  const int tid = threadIdx.x;
  if (bid < 8192) {
    int i = bid * 256 + tid;
    float4 v = ((const float4*)hs)[i];
    __hip_bfloat162 lo = __float22bfloat162_rn(make_float2(v.x, v.y));
    __hip_bfloat162 hi = __float22bfloat162_rn(make_float2(v.z, v.w));
    ((__hip_bfloat162*)Xb)[2*i]   = lo;
    ((__hip_bfloat162*)Xb)[2*i+1] = hi;
    return;
  }
  const float* W; __hip_bfloat16* Wt; int N, n0, k0;
  if (bid < 20480) {
    int b2 = bid - 8192;
    W = Wqkv; Wt = WqkvT; N = 6144;
    n0 = (b2 % 192) * 32; k0 = (b2 / 192) * 32;
  } else {
    int b3 = bid - 20480;
    W = Wd; Wt = WdT; N = 2048;
    n0 = (b3 % 64) * 32; k0 = (b3 / 64) * 32;
  }
  const int tx = tid & 31, ty = tid >> 5;
  #pragma unroll
  for (int i = 0; i < 32; i += 8)
    tile[ty + i][tx] = W[(size_t)(k0 + ty + i) * N + n0 + tx];
  __syncthreads();
  #pragma unroll
  for (int i = 0; i < 32; i += 8)
    Wt[(size_t)(n0 + ty + i) * 2048 + k0 + tx] = __float2bfloat16(tile[tx][ty + i]);
}

// ---------------- pure bf16 transpose: Vup [bh][k][d] -> Vt [bh][d][k] ----------------
__global__ __launch_bounds__(256) void k_vtrans2(const __hip_bfloat16* __restrict__ Vup,
                                                 __hip_bfloat16* __restrict__ Vt) {
  __shared__ unsigned short tile[32][33];
  int k0 = blockIdx.x * 32, d0 = blockIdx.y * 32, bh = blockIdx.z;
  int tx = threadIdx.x, ty = threadIdx.y;
  const unsigned short* src = (const unsigned short*)Vup;
  unsigned short* dst = (unsigned short*)Vt;
  #pragma unroll
  for (int i = 0; i < 32; i += 8)
    tile[ty + i][tx] = src[((size_t)bh * S_LEN + (k0 + ty + i)) * HDIM + d0 + tx];
  __syncthreads();
  #pragma unroll
  for (int i = 0; i < 32; i += 8)
    dst[((size_t)bh * HDIM + (d0 + ty + i)) * S_LEN + k0 + tx] = tile[tx][ty + i];
}

// ---------------- 128x128 bf16 MFMA GEMM core, BK=64 single-barrier-pair ----------------
// LDS 32 KB: A0 @0, B0 @8192, A1 @16384, B1 @24576 (each 8 KB, 64-B row stride).
__device__ __forceinline__ void gemm128(const char* __restrict__ A, const char* __restrict__ Bt,
                                        int K, long rowA0, long rowB0, char* lds,
                                        f32x4 (&acc)[4][4]) {
  const int tid  = threadIdx.x;
  const int lane = tid & 63;
  const int wave = tid >> 6;
  const int wm = wave >> 1, wn = wave & 1;
  const int l4  = lane >> 2;
  const int lkb = (lane & 3) * 16;
  const int rlo = lane & 15;
  const int khi = (lane >> 4) * 16;
  const long strA = (long)K * 2;
  for (int k0 = 0; k0 < K; k0 += 64) {
    // stage both 32-K halves (8 loads/thread in flight), then one barrier
    #pragma unroll
    for (int half = 0; half < 2; half++) {
      const long kof = (long)(k0 + half * 32) * 2;
      char* ldsA = lds + half * 16384;
      char* ldsB = lds + half * 16384 + 8192;
      #pragma unroll
      for (int q = 0; q < 2; q++) {
        long ra = rowA0 + wave*32 + q*16 + l4;
        const char* ga = A + ra*strA + kof + lkb;
        __builtin_amdgcn_global_load_lds((const __attribute__((address_space(1))) void*)ga,
            (__attribute__((address_space(3))) void*)(ldsA + wave*2048 + q*1024), 16, 0, 0);
        long rbn = rowB0 + wave*32 + q*16 + l4;
        const char* gb = Bt + rbn*strA + kof + lkb;
        __builtin_amdgcn_global_load_lds((const __attribute__((address_space(1))) void*)gb,
            (__attribute__((address_space(3))) void*)(ldsB + wave*2048 + q*1024), 16, 0, 0);
      }
    }
    __syncthreads();
    #pragma unroll
    for (int half = 0; half < 2; half++) {
      const char* ldsA = lds + half * 16384;
      const char* ldsB = lds + half * 16384 + 8192;
      bf16x8 af[4], bfr[4];
      #pragma unroll
      for (int mf = 0; mf < 4; mf++)
        af[mf] = *(const bf16x8*)(ldsA + (wm*64 + mf*16 + rlo)*64 + khi);
      #pragma unroll
      for (int nf = 0; nf < 4; nf++)
        bfr[nf] = *(const bf16x8*)(ldsB + (wn*64 + nf*16 + rlo)*64 + khi);
      #pragma unroll
      for (int mf = 0; mf < 4; mf++)
        #pragma unroll
        for (int nf = 0; nf < 4; nf++)
          acc[mf][nf] = __builtin_amdgcn_mfma_f32_16x16x32_bf16(af[mf], bfr[nf], acc[mf][nf], 0, 0, 0);
    }
    __syncthreads();
  }
}

// ---------------- GEMM qkv + bias + RoPE + scatter ----------------
__global__ __launch_bounds__(256, 3) void k_gemm_qkv(const __hip_bfloat16* __restrict__ Xb,
    const __hip_bfloat16* __restrict__ WqkvT, const float* __restrict__ bqkv,
    const int* __restrict__ pid,
    __hip_bfloat16* __restrict__ Qb, __hip_bfloat16* __restrict__ Kb, float* __restrict__ Vf) {
  __shared__ __align__(16) char lds[32768];
  f32x4 acc[4][4];
  #pragma unroll
  for (int m = 0; m < 4; m++)
    #pragma unroll
    for (int n = 0; n < 4; n++)
      #pragma unroll
      for (int r = 0; r < 4; r++) acc[m][n][r] = 0.f;
  // XCD swizzle + L2 blocking: XCD x owns bn in [x*6, x*6+6), all 32 bm.
  // Order within XCD: bm-chunk(4 of 8) x bn(6) x bm-within(8) -> A panel (4MB) L2-resident.
  int flat = blockIdx.y * 32 + blockIdx.x;
  int xcd = flat & 7, i = flat >> 3;       // i in [0,192)
  int c = i / 48, r = i % 48;
  int bn_l = r >> 3, bm_l = r & 7;
  int bm = c * 8 + bm_l;
  int bn = xcd * 6 + bn_l;
  gemm128((const char*)Xb, (const char*)WqkvT, HID, (long)bm*128, (long)bn*128, lds, acc);
  const int lane = threadIdx.x & 63, wave = threadIdx.x >> 6;
  const int wm = wave >> 1, wn = wave & 1;
  const int colbase = bn*128 + wn*64;
  const int rowbase = bm*128 + wm*64 + (lane >> 4) * 4;
  // bias
  #pragma unroll
  for (int nf = 0; nf < 4; nf++) {
    int col = colbase + nf*16 + (lane & 15);
    float bias = bqkv[col];
    #pragma unroll
    for (int mf = 0; mf < 4; mf++)
      #pragma unroll
      for (int r2 = 0; r2 < 4; r2++) acc[mf][nf][r2] += bias;
  }
  // RoPE: pair (i, i+16) in frags nf=0,1 at same lane iff colbase%384 in {0,128}
  const int jb = colbase % 384;
  if (jb == 0 || jb == 128) {
    const int ii = lane & 15;
    const float invf = exp2f(-(float)ii * 0.8304820237218406f); // 10000^(-i/16)
    #pragma unroll
    for (int mf = 0; mf < 4; mf++) {
      #pragma unroll
      for (int r2 = 0; r2 < 4; r2++) {
        int row = rowbase + mf*16 + r2;
        int b = row >> 10, s = row & 1023;
        float th = (float)pid[b * S_LEN + s] * invf;
        float sn, cs;
        sincosf(th, &sn, &cs);
        float x1 = acc[mf][0][r2], x2 = acc[mf][1][r2];
        acc[mf][0][r2] = x1*cs - x2*sn;
        acc[mf][1][r2] = x2*cs + x1*sn;
      }
    }
  }
  // scatter
  #pragma unroll
  for (int mf = 0; mf < 4; mf++) {
    #pragma unroll
    for (int nf = 0; nf < 4; nf++) {
      int col = colbase + nf*16 + (lane & 15);
      int h = col / 384, j = col % 384;
      #pragma unroll
      for (int r2 = 0; r2 < 4; r2++) {
        int row = rowbase + mf*16 + r2;
        int b = row >> 10, s = row & 1023;
        size_t base = ((size_t)(b*NHEAD + h)*S_LEN + s)*HDIM;
        float v = acc[mf][nf][r2];
        if (j < 128)      Qb[base + j]       = __float2bfloat16(v);
        else if (j < 256) Kb[base + j - 128] = __float2bfloat16(v);
        else              Vf[base + j - 256] = v;
      }
    }
  }
}

// ---------------- GEMM out-proj + bias ----------------
__global__ __launch_bounds__(256, 3) void k_gemm_out(const __hip_bfloat16* __restrict__ Ab,
    const __hip_bfloat16* __restrict__ WdT, const float* __restrict__ bd,
    float* __restrict__ Out) {
  __shared__ __align__(16) char lds[32768];
  f32x4 acc[4][4];
  #pragma unroll
  for (int m = 0; m < 4; m++)
    #pragma unroll
    for (int n = 0; n < 4; n++)
      #pragma unroll
      for (int r = 0; r < 4; r++) acc[m][n][r] = 0.f;
  // XCD swizzle + L2 blocking: XCD x owns bn in [x*2, x*2+2), all 32 bm.
  // Order: bm-chunk(4 of 8) x bn(2) x bm-within(8).
  int flat = blockIdx.y * 32 + blockIdx.x;
  int xcd = flat & 7, i = flat >> 3;       // i in [0,64)
  int c = i / 16, r = i % 16;
  int bn_l = r >> 3, bm_l = r & 7;
  int bm = c * 8 + bm_l;
  int bn = xcd * 2 + bn_l;
  gemm128((const char*)Ab, (const char*)WdT, HID, (long)bm*128, (long)bn*128, lds, acc);
  const int lane = threadIdx.x & 63, wave = threadIdx.x >> 6;
  const int wm = wave >> 1, wn = wave & 1;
  const int colbase = bn*128 + wn*64;
  const int rowbase = bm*128 + wm*64 + (lane >> 4) * 4;
  #pragma unroll
  for (int nf = 0; nf < 4; nf++) {
    int col = colbase + nf*16 + (lane & 15);
    float bias = bd[col];
    #pragma unroll
    for (int mf = 0; mf < 4; mf++)
      #pragma unroll
      for (int r2 = 0; r2 < 4; r2++) {
        int row = rowbase + mf*16 + r2;
        Out[(size_t)row * HID + col] = acc[mf][nf][r2] + bias;
      }
  }
}

// ---------------- banded flash attention (R5 structure + occupancy cap) ----------------
__device__ __forceinline__ bf16x8 lds_load8(const char* p) {
  bf16x4 lo = *(const bf16x4*)p;
  bf16x4 hi = *(const bf16x4*)(p + 8);
  bf16x8 v;
  v[0]=lo[0]; v[1]=lo[1]; v[2]=lo[2]; v[3]=lo[3];
  v[4]=hi[0]; v[5]=hi[1]; v[6]=hi[2]; v[7]=hi[3];
  return v;
}

template<int PHASE>
__global__ __launch_bounds__(256, 3) void k_flash(const __hip_bfloat16* __restrict__ Qb,
    const __hip_bfloat16* __restrict__ Kb, const __hip_bfloat16* __restrict__ Vt,
    const float* __restrict__ amask,
    float* __restrict__ Pstart, float* __restrict__ PbT,
    __hip_bfloat16* __restrict__ Aout) {
  const int q0 = blockIdx.x * 64;
  const int bh = blockIdx.y;                 // PHASE0: h, PHASE1: b*16+h
  const int b  = PHASE ? (bh >> 4) : 0;
  const int h  = PHASE ? (bh & 15) : bh;
  const int tid = threadIdx.x;
  const int w = tid >> 6;
  const int lane = tid & 63;
  const int l15 = lane & 15, g = lane >> 4;

  const int t1 = (q0 >= 128) ? max(128, (q0 - 103) & ~31) : 128;
  const int nt1 = (q0 + 64 > t1) ? (q0 + 64 - t1) / 32 : 0;
  const int ntiles = 4 + nt1;
  const int nfrags = ntiles * 2;             // <= 20

  __shared__ float redm[4][64];
  __shared__ float reds[4][64];
  __shared__ __align__(16) char plds[(PHASE ? 64 * PLDS_STRIDE : 16)];

  const size_t qkbase = (size_t)bh * S_LEN;

  bf16x8 af[4][4];
  #pragma unroll
  for (int mi = 0; mi < 4; mi++)
    #pragma unroll
    for (int dt = 0; dt < 4; dt++)
      af[mi][dt] = *(const bf16x8*)(Qb + (qkbase + q0 + mi*16 + l15)*HDIM + dt*32 + g*8);

  int kb[5];
  #pragma unroll
  for (int fi = 0; fi < 5; fi++) {
    int f = w + fi*4;
    if (f < nfrags) {
      int ti = f >> 1;
      int kt = (ti < 4) ? ti*32 : t1 + (ti-4)*32;
      kb[fi] = kt + (f & 1)*16;
    } else kb[fi] = -1;
  }

  f32x4 sacc[4][5];
  #pragma unroll
  for (int mi = 0; mi < 4; mi++)
    #pragma unroll
    for (int fi = 0; fi < 5; fi++)
      #pragma unroll
      for (int r = 0; r < 4; r++) sacc[mi][fi][r] = 0.f;

  #pragma unroll
  for (int fi = 0; fi < 5; fi++) {
    if (kb[fi] < 0) continue;
    #pragma unroll
    for (int dt = 0; dt < 4; dt++) {
      bf16x8 bfr = *(const bf16x8*)(Kb + (qkbase + kb[fi] + l15)*HDIM + dt*32 + g*8);
      #pragma unroll
      for (int mi = 0; mi < 4; mi++)
        sacc[mi][fi] = __builtin_amdgcn_mfma_f32_16x16x32_bf16(af[mi][dt], bfr, sacc[mi][fi], 0, 0, 0);
    }
  }

  #pragma unroll
  for (int fi = 0; fi < 5; fi++) {
    if (kb[fi] < 0) continue;
    int kcol = kb[fi] + l15;
    float amv = amask[b * S_LEN + kcol];
    #pragma unroll
    for (int mi = 0; mi < 4; mi++)
      #pragma unroll
      for (int r = 0; r < 4; r++) {
        int q = q0 + mi*16 + g*4 + r;
        bool ok = (kcol <= q) && ((kcol < SB) || (kcol + RB >= q));
        sacc[mi][fi][r] = ok ? sacc[mi][fi][r] * 0.08838834764831845f + amv : -3.0e38f;
      }
  }

  float rmax[4][4];
  #pragma unroll
  for (int mi = 0; mi < 4; mi++)
    #pragma unroll
    for (int r = 0; r < 4; r++) {
      float m = -3.4e38f;
      #pragma unroll
      for (int fi = 0; fi < 5; fi++)
        if (kb[fi] >= 0) m = fmaxf(m, sacc[mi][fi][r]);
      #pragma unroll
      for (int d = 1; d < 16; d <<= 1) m = fmaxf(m, __shfl_xor(m, d));
      rmax[mi][r] = m;
    }
  if (l15 == 0)
    #pragma unroll
    for (int mi = 0; mi < 4; mi++)
      #pragma unroll
      for (int r = 0; r < 4; r++) redm[w][mi*16 + g*4 + r] = rmax[mi][r];
  __syncthreads();
  #pragma unroll
  for (int mi = 0; mi < 4; mi++)
    #pragma unroll
    for (int r = 0; r < 4; r++) {
      int q = mi*16 + g*4 + r;
      rmax[mi][r] = fmaxf(fmaxf(redm[0][q], redm[1][q]), fmaxf(redm[2][q], redm[3][q]));
    }

  float rsum[4][4];
  #pragma unroll
  for (int mi = 0; mi < 4; mi++)
    #pragma unroll
    for (int r = 0; r < 4; r++) rsum[mi][r] = 0.f;
  #pragma unroll
  for (int fi = 0; fi < 5; fi++) {
    if (kb[fi] < 0) continue;
    #pragma unroll
    for (int mi = 0; mi < 4; mi++)
      #pragma unroll
      for (int r = 0; r < 4; r++) {
        float e = __expf(sacc[mi][fi][r] - rmax[mi][r]);
        sacc[mi][fi][r] = e;
        rsum[mi][r] += e;
      }
  }
  #pragma unroll
  for (int mi = 0; mi < 4; mi++)
    #pragma unroll
    for (int r = 0; r < 4; r++) {
      float s = rsum[mi][r];
      #pragma unroll
      for (int d = 1; d < 16; d <<= 1) s += __shfl_xor(s, d);
      rsum[mi][r] = s;
    }
  if (l15 == 0)
    #pragma unroll
    for (int mi = 0; mi < 4; mi++)
      #pragma unroll
      for (int r = 0; r < 4; r++) reds[w][mi*16 + g*4 + r] = rsum[mi][r];
  __syncthreads();
  float inv[4][4];
  #pragma unroll
  for (int mi = 0; mi < 4; mi++)
    #pragma unroll
    for (int r = 0; r < 4; r++) {
      int q = mi*16 + g*4 + r;
      inv[mi][r] = 1.0f / (reds[0][q] + reds[1][q] + reds[2][q] + reds[3][q]);
    }

  if constexpr (PHASE == 0) {
    #pragma unroll
    for (int fi = 0; fi < 5; fi++) {
      if (kb[fi] < 0) continue;
      int kcol = kb[fi] + l15;
      #pragma unroll
      for (int mi = 0; mi < 4; mi++)
        #pragma unroll
        for (int r = 0; r < 4; r++) {
          int q = q0 + mi*16 + g*4 + r;
          float p = sacc[mi][fi][r] * inv[mi][r];
          if (kcol < 128)
            Pstart[((size_t)h*128 + kcol)*S_LEN + q] = p;
          if (kcol >= SB && kcol < 1023 && kcol <= q && q - kcol <= RB)
            PbT[((size_t)h*920 + (kcol - SB))*104 + (q - kcol)] = p;
        }
    }
  } else {
    #pragma unroll
    for (int fi = 0; fi < 5; fi++) {
      if (kb[fi] < 0) continue;
      int cc = (w + fi*4)*16 + l15;
      #pragma unroll
      for (int mi = 0; mi < 4; mi++)
        #pragma unroll
        for (int r = 0; r < 4; r++) {
          int qs = mi*16 + g*4 + r;
          *(__hip_bfloat16*)(plds + qs*PLDS_STRIDE + cc*2) =
              __float2bfloat16(sacc[mi][fi][r] * inv[mi][r]);
        }
    }
    __syncthreads();
    f32x4 pacc[4][2];
    #pragma unroll
    for (int mi = 0; mi < 4; mi++)
      #pragma unroll
      for (int nj = 0; nj < 2; nj++)
        #pragma unroll
        for (int r = 0; r < 4; r++) pacc[mi][nj][r] = 0.f;
    for (int ti = 0; ti < ntiles; ti++) {
      int kt = (ti < 4) ? ti*32 : t1 + (ti-4)*32;
      int cb = ti*32;
      bf16x8 pa[4];
      #pragma unroll
      for (int mi = 0; mi < 4; mi++)
        pa[mi] = lds_load8(plds + (mi*16 + l15)*PLDS_STRIDE + (cb + g*8)*2);
      #pragma unroll
      for (int nj = 0; nj < 2; nj++) {
        int d = w*32 + nj*16 + l15;
        bf16x8 vb = *(const bf16x8*)(Vt + ((size_t)bh*HDIM + d)*S_LEN + kt + g*8);
        #pragma unroll
        for (int mi = 0; mi < 4; mi++)
          pacc[mi][nj] = __builtin_amdgcn_mfma_f32_16x16x32_bf16(pa[mi], vb, pacc[mi][nj], 0, 0, 0);
      }
    }
    #pragma unroll
    for (int mi = 0; mi < 4; mi++)
      #pragma unroll
      for (int nj = 0; nj < 2; nj++)
        #pragma unroll
        for (int r = 0; r < 4; r++) {
          int q = q0 + mi*16 + g*4 + r;
          int d = w*32 + nj*16 + l15;
          Aout[((size_t)b*S_LEN + q)*HID + h*HDIM + d] = __float2bfloat16(pacc[mi][nj][r]);
        }
  }
}

// ---------------- stats: sstart + band merged (wave-per-column prefix scans) ----------------
__global__ __launch_bounds__(256) void k_scans(const float* __restrict__ Pstart,
                                               const float* __restrict__ PbT,
                                               float* __restrict__ Sstart,
                                               float* __restrict__ Band) {
  int lane = threadIdx.x & 63;
  if (blockIdx.x < 412) {
    int wid = blockIdx.x*4 + (threadIdx.x >> 6);
    if (wid >= NHEAD * SB) return;
    int h = wid / SB, k = wid % SB;
    const float* col = Pstart + ((size_t)h*128 + k)*S_LEN;
    float carry = 0.f;
    for (int seg = 0; seg < 16; seg++) {
      int q = seg*64 + lane;
      float v = col[q];
      #pragma unroll
      for (int d = 1; d < 64; d <<= 1) {
        float u = __shfl_up(v, d);
        if (lane >= d) v += u;
      }
      float tot = carry + v;
      int t = q + 1;
      if (t >= TMIN && t < S_LEN)
        Sstart[((size_t)h*SB + k)*NT + (t - TMIN)] = tot;
      carry += __shfl(v, 63);
    }
  } else {
    int wid = (blockIdx.x - 412)*4 + (threadIdx.x >> 6);
    if (wid >= NHEAD * 920) return;
    int h = wid / 920, kk = wid % 920;
    int k = kk + SB;
    const float* col = PbT + ((size_t)h*920 + kk)*104;
    float carry = 0.f;
    #pragma unroll
    for (int seg = 0; seg < 2; seg++) {
      int i = seg*64 + lane;
      bool valid = (i <= 102) && (k + i <= 1022);
      float v = valid ? col[i] : 0.f;
      #pragma unroll
      for (int d = 1; d < 64; d <<= 1) {
        float u = __shfl_up(v, d);
        if (lane >= d) v += u;
      }
      float tot = carry + v;
      int t = k + i + 1;
      if (valid && t >= TMIN && t < S_LEN) {
        int j = 102 - i;
        Band[((size_t)h*S_LEN + t)*SB + j] = tot;
      }
      carry += __shfl(v, 63);
    }
  }
}

// ---------------- prob + threefry bernoulli ----------------
__global__ __launch_bounds__(64) void k_mask(const float* __restrict__ Sstart,
    const float* __restrict__ Band, float* __restrict__ Mask) {
  const int t = TMIN + blockIdx.x;
  const int lane = threadIdx.x;
  const int h = lane >> 2, j = lane & 3;
  const float* bb = Band + ((size_t)h*S_LEN + t)*SB;
  float mx = -3.4e38f;
  for (int i = j; i < SB; i += 4)
    mx = fmaxf(mx, Sstart[((size_t)h*SB + i)*NT + (t - TMIN)]);
  for (int i = j; i < RB; i += 4) mx = fmaxf(mx, bb[i]);
  mx = fmaxf(mx, __shfl_xor(mx, 1));
  mx = fmaxf(mx, __shfl_xor(mx, 2));
  if (j == 0) {
    float prob = bb[0] / mx;
    prob = fminf(fmaxf(prob, 0.f), 1.f);
    unsigned a0, a1, b0, b1;
    tf2x32(0u, 42u, 0u, (unsigned)t, a0, a1);
    tf2x32(a0, a1, 0u, (unsigned)h, b0, b1);
    float u = tfu(b0 ^ b1);
    Mask[t*NHEAD + h] = (u < prob) ? 1.f : 0.f;
  }
}

// ---------------- fused CAM scan + vupdate -> Vup bf16 [bh][p][d] ----------------
__global__ __launch_bounds__(64) void k_scan(const float* __restrict__ Vf,
    const float* __restrict__ Mask, __hip_bfloat16* __restrict__ Vup) {
  const int blk = blockIdx.x;       // 0..127
  const int bh = blk >> 1, dc = blk & 1;
  const int h = bh & 15;
  const int lane = threadIdx.x;
  const int col = dc*64 + lane;
  __shared__ float ring[RB * 64];   // w ring
  __shared__ float pring[RB * 64];  // P ring
  __shared__ float marr[NT];
  for (int i = lane; i < NT; i += 64) marr[i] = Mask[(TMIN + i)*NHEAD + h];
  __syncthreads();
  const size_t vbase = (size_t)bh * S_LEN * HDIM + col;
  const size_t obase = (size_t)bh * S_LEN * HDIM + col;
  #pragma unroll 4
  for (int p = 0; p <= 103; p++)
    Vup[obase + (size_t)p * HDIM] = __float2bfloat16(Vf[vbase + (size_t)p * HDIM]);

  float S = 0.f, P = 0.f;
  float cur[8], nxt[8];
  #pragma unroll
  for (int u = 0; u < 8; u++)
    cur[u] = Vf[vbase + (size_t)(TMIN - RB + u) * HDIM];
  for (int t0 = TMIN; t0 < S_LEN; t0 += 8) {
    #pragma unroll
    for (int u = 0; u < 8; u++) {
      int t = t0 + 8 + u;
      if (t < S_LEN + 8) nxt[u] = Vf[vbase + (size_t)min(t - RB, S_LEN - 1) * HDIM];
    }
    float olds[8], plo[8];
    #pragma unroll
    for (int u = 0; u < 8; u++) {
      int t = t0 + u;
      olds[u] = (t >= TMIN + RB) ? ring[(t % RB)*64 + lane] : 0.f;
      plo[u]  = (t >= TMIN + RB) ? pring[(t % RB)*64 + lane] : 0.f;  // = P(t-103)
    }
    #pragma unroll
    for (int u = 0; u < 8; u++) {
      int t = t0 + u;
      float a = fmaf(S, (1.f/103.f), cur[u]);
      float w = marr[t - TMIN] * a;
      P += w;
      float vnext = (u < 7) ? cur[u + 1] : nxt[0];
      float Plo = (t <= 308) ? 0.f : plo[u];
      Vup[obase + (size_t)(t - 102) * HDIM] = __float2bfloat16(vnext + (P - Plo) * (1.f/103.f));
      pring[(t % RB)*64 + lane] = P;
      ring[(t % RB)*64 + lane] = w;
      S += w - olds[u];
      cur[u] = nxt[u];
    }
  }
  const float Pfin = P;
  for (int p = 922; p <= 1023; p++) {
    float Plo = pring[((p - 1) % RB)*64 + lane];
    float v = Vf[vbase + (size_t)p * HDIM];
    Vup[obase + (size_t)p * HDIM] = __float2bfloat16(v + (Pfin - Plo) * (1.f/103.f));
  }
}

extern "C" void kernel_launch(void* const* d_in, const int* in_sizes, int n_in,
                              void* d_out, int out_size, void* d_ws, size_t ws_size,
                              hipStream_t stream) {
  const float* hs    = (const float*)d_in[0];
  const float* amask = (const float*)d_in[1];
  const int*   pid   = (const int*)d_in[2];
  const float* Wqkv  = (const float*)d_in[3];
  const float* bqkv  = (const float*)d_in[4];
  const float* Wd    = (const float*)d_in[5];
  const float* bd    = (const float*)d_in[6];
  float* Out = (float*)d_out;

  char* ws = (char*)d_ws;
  size_t off = 0;
  auto alloc = [&](size_t bytes) {
    char* p = ws + off;
    off += (bytes + 255) & ~(size_t)255;
    return p;
  };
  __hip_bfloat16* Xb     = (__hip_bfloat16*)alloc(16777216);  // 4096x2048 bf16
  __hip_bfloat16* WqkvT  = (__hip_bfloat16*)alloc(25165824);  // 6144x2048 bf16
  __hip_bfloat16* WdT    = (__hip_bfloat16*)alloc(8388608);   // 2048x2048 bf16
  __hip_bfloat16* Qb     = (__hip_bfloat16*)alloc(16777216);  // (4,16,1024,128) bf16
  __hip_bfloat16* Kb     = (__hip_bfloat16*)alloc(16777216);
  float*          Vf     = (float*)alloc(33554432);           // (4,16,1024,128) f32
  __hip_bfloat16* Vup    = (__hip_bfloat16*)alloc(16777216);  // (64,1024,128) bf16
  __hip_bfloat16* Vt     = (__hip_bfloat16*)alloc(16777216);  // (64,128,1024) bf16
  float*          Pstart = (float*)alloc(8388608);            // (16,128,1024) f32
  float*          PbT    = (float*)alloc(6123520);            // (16,920,104) f32
  float*          Sstart = (float*)alloc(5392256);            // (16,103,818) f32
  float*          Band   = (float*)alloc(6750208);            // (16,1024,103) f32
  float*          Mask   = (float*)alloc(65536);              // (1024,16) f32
  __hip_bfloat16* Aout   = (__hip_bfloat16*)alloc(16777216);  // 4096x2048 bf16

  k_prep<<<24576, 256, 0, stream>>>(hs, Wqkv, Wd, Xb, WqkvT, WdT);
  k_gemm_qkv<<<dim3(32, 48), 256, 0, stream>>>(Xb, WqkvT, bqkv, pid, Qb, Kb, Vf);
  k_flash<0><<<dim3(16, 16), 256, 0, stream>>>(Qb, Kb, nullptr, amask, Pstart, PbT, nullptr);
  k_scans<<<4092, 256, 0, stream>>>(Pstart, PbT, Sstart, Band);
  k_mask<<<818, 64, 0, stream>>>(Sstart, Band, Mask);
  k_scan<<<128, 64, 0, stream>>>(Vf, Mask, Vup);
  k_vtrans2<<<dim3(32, 4, 64), dim3(32, 8), 0, stream>>>(Vup, Vt);
  k_flash<1><<<dim3(16, 64), 256, 0, stream>>>(Qb, Kb, Vt, amask, nullptr, nullptr, Aout);
  k_gemm_out<<<dim3(32, 16), 256, 0, stream>>>(Aout, WdT, bd, Out);
}